// Round 15
// baseline (448.482 us; speedup 1.0000x reference)
//
#include <hip/hip_runtime.h>
#include <stdint.h>

// CrossWinAttention: b=4 n=4 x=y=8 w1=w2=8 d=128, H=4 Dh=32, L=64, NW=256, BH=16.
#define LN_EPS 1e-5f
#define SCALE 0.17677669529663687f   // 32^-0.5
#define KEEPQ 192

typedef __attribute__((ext_vector_type(8))) short short8v;   // 8 bf16
typedef __attribute__((ext_vector_type(4))) float float4v;

__device__ __forceinline__ short f2bf(float x) {             // RNE f32->bf16
  uint32_t u = __float_as_uint(x);
  uint32_t r = (u + 0x7FFFu + ((u >> 16) & 1u)) >> 16;
  return (short)r;
}
__device__ __forceinline__ float bf2f(short s) {
  return __uint_as_float(((uint32_t)(uint16_t)s) << 16);
}
__device__ __forceinline__ uint32_t pk2(short a, short b) {
  return (uint32_t)(uint16_t)a | ((uint32_t)(uint16_t)b << 16);
}
__device__ __forceinline__ void split3(float x, short &h, short &m, short &l) {
  h = f2bf(x); float r1 = x - bf2f(h);
  m = f2bf(r1); float r2 = r1 - bf2f(m);
  l = f2bf(r2);
}
__device__ __forceinline__ uint32_t fmap(float x) {          // order-preserving map
  uint32_t bb = __float_as_uint(x);
  if ((bb & 0x7FFFFFFFu) == 0u) bb = 0u;                     // -0 -> +0
  return (bb & 0x80000000u) ? ~bb : (bb | 0x80000000u);
}
__device__ __forceinline__ float unmap(uint32_t m) {         // inverse of fmap
  uint32_t b = (m & 0x80000000u) ? (m & 0x7FFFFFFFu) : ~m;
  return __uint_as_float(b);
}

// Exact top-k over 256 values, 4 per lane (element index = lane + 64*s).
// Tie-break: smaller index wins. All 64 lanes must participate.
__device__ __forceinline__ void topk_sel(const float v[4], int k, int lane, bool sel[4]) {
  uint32_t u[4];
  #pragma unroll
  for (int s = 0; s < 4; ++s) u[s] = fmap(v[s]);
  uint32_t prefix = 0u;
  bool exact = false;
  for (int bit = 31; bit >= 0; --bit) {
    uint32_t cand = prefix | (1u << bit);
    int c = 0;
    #pragma unroll
    for (int s = 0; s < 4; ++s) c += __popcll(__ballot(u[s] >= cand));
    if (c >= k) {
      prefix = cand;
      if (c == k) { exact = true; break; }
    }
  }
  if (exact) {
    #pragma unroll
    for (int s = 0; s < 4; ++s) sel[s] = (u[s] >= prefix);
    return;
  }
  const uint32_t T = prefix;
  int gt = 0;
  unsigned long long eb[4];
  #pragma unroll
  for (int s = 0; s < 4; ++s) {
    gt += __popcll(__ballot(u[s] > T));
    eb[s] = __ballot(u[s] == T);
  }
  const int need = k - gt;
  const unsigned long long lm = (1ull << lane) - 1ull;
  int base = 0;
  #pragma unroll
  for (int s = 0; s < 4; ++s) {
    int before = base + __popcll(eb[s] & lm);
    sel[s] = (u[s] > T) || ((u[s] == T) && (before < need));
    base += __popcll(eb[s]);
  }
}

// ---------------- Kernel 1: LN + QKV projection (FROZEN numerics) ----------------
__global__ __launch_bounds__(256) void k_lnproj(
    const float* __restrict__ xq, const float* __restrict__ xk, const float* __restrict__ xv,
    const float* __restrict__ gq, const float* __restrict__ beq,
    const float* __restrict__ gk, const float* __restrict__ bek,
    const float* __restrict__ gv, const float* __restrict__ bev,
    const float* __restrict__ wq, const float* __restrict__ biq,
    const float* __restrict__ wk, const float* __restrict__ bik,
    const float* __restrict__ wv, const float* __restrict__ biv,
    float* __restrict__ qh, short* __restrict__ k0, short* __restrict__ k1,
    short* __restrict__ k2, short* __restrict__ vt)
{
  __shared__ float xs[64 * 132];
  const int tile = blockIdx.x;
  const int t = blockIdx.y;
  const float* x  = (t == 0) ? xq : (t == 1) ? xk : xv;
  const float* g  = (t == 0) ? gq : (t == 1) ? gk : gv;
  const float* be = (t == 0) ? beq : (t == 1) ? bek : bev;
  const float* W  = (t == 0) ? wq : (t == 1) ? wk : wv;
  const float* bi = (t == 0) ? biq : (t == 1) ? bik : biv;
  const int tid = threadIdx.x;

  const float4* xg = (const float4*)(x + (size_t)tile * 64 * 128);
  #pragma unroll
  for (int i = 0; i < 8; ++i) {
    int idx = tid + i * 256;
    int r = idx >> 5;
    int c = (idx & 31) * 4;
    *(float4*)&xs[r * 132 + c] = xg[idx];
  }
  __syncthreads();

  {
    int r = tid >> 2, p = tid & 3;
    float s = 0.f, sq = 0.f;
    #pragma unroll
    for (int c = 0; c < 32; ++c) {
      float vv = xs[r * 132 + p * 32 + c];
      s += vv; sq += vv * vv;
    }
    s += __shfl_xor(s, 1, 64); sq += __shfl_xor(sq, 1, 64);
    s += __shfl_xor(s, 2, 64); sq += __shfl_xor(sq, 2, 64);
    float mean = s * (1.0f / 128.0f);
    float var = sq * (1.0f / 128.0f) - mean * mean;
    float rstd = rsqrtf(var + LN_EPS);
    #pragma unroll
    for (int c = 0; c < 32; ++c) {
      int cc = p * 32 + c;
      xs[r * 132 + cc] = (xs[r * 132 + cc] - mean) * rstd * g[cc] + be[cc];
    }
  }
  __syncthreads();

  const int ty = tid >> 4, tx = tid & 15;
  float acc[4][8];
  #pragma unroll
  for (int i = 0; i < 4; ++i)
    #pragma unroll
    for (int j = 0; j < 8; ++j) acc[i][j] = 0.f;

  #pragma unroll 2
  for (int kk = 0; kk < 128; kk += 4) {
    float aa[4][4];
    #pragma unroll
    for (int i = 0; i < 4; ++i)
      *(float4*)&aa[i][0] = *(const float4*)&xs[(ty * 4 + i) * 132 + kk];
    #pragma unroll
    for (int t2 = 0; t2 < 4; ++t2) {
      const float4 w0 = *(const float4*)&W[(kk + t2) * 128 + tx * 8];
      const float4 w1 = *(const float4*)&W[(kk + t2) * 128 + tx * 8 + 4];
      #pragma unroll
      for (int i = 0; i < 4; ++i) {
        acc[i][0] = fmaf(aa[i][t2], w0.x, acc[i][0]);
        acc[i][1] = fmaf(aa[i][t2], w0.y, acc[i][1]);
        acc[i][2] = fmaf(aa[i][t2], w0.z, acc[i][2]);
        acc[i][3] = fmaf(aa[i][t2], w0.w, acc[i][3]);
        acc[i][4] = fmaf(aa[i][t2], w1.x, acc[i][4]);
        acc[i][5] = fmaf(aa[i][t2], w1.y, acc[i][5]);
        acc[i][6] = fmaf(aa[i][t2], w1.z, acc[i][6]);
        acc[i][7] = fmaf(aa[i][t2], w1.w, acc[i][7]);
      }
    }
  }

  float bias[8];
  #pragma unroll
  for (int j = 0; j < 8; ++j) bias[j] = bi[tx * 8 + j];
  const int b  = tile >> 8;
  const int n  = (tile >> 6) & 3;
  const int l  = ((tile >> 3) & 7) * 8 + (tile & 7);
  const int h  = tx >> 2;
  const int dh0 = (tx & 3) * 8;
  const size_t win = (size_t)(b * 4 + h) * 64 + l;

  if (t == 0) {
    #pragma unroll
    for (int i = 0; i < 4; ++i) {
      int j = n * 64 + ty * 4 + i;
      size_t off = (win * 256 + j) * 32 + dh0;
      float4 o0 = make_float4(acc[i][0] + bias[0], acc[i][1] + bias[1],
                              acc[i][2] + bias[2], acc[i][3] + bias[3]);
      float4 o1 = make_float4(acc[i][4] + bias[4], acc[i][5] + bias[5],
                              acc[i][6] + bias[6], acc[i][7] + bias[7]);
      *(float4*)&qh[off] = o0;
      *(float4*)&qh[off + 4] = o1;
    }
  } else if (t == 1) {
    #pragma unroll
    for (int i = 0; i < 4; ++i) {
      int j = n * 64 + ty * 4 + i;
      size_t off = (win * 256 + j) * 32 + dh0;
      short hh[8], mm[8], ll[8];
      #pragma unroll
      for (int jj = 0; jj < 8; ++jj) {
        float o = acc[i][jj] + bias[jj];
        split3(o, hh[jj], mm[jj], ll[jj]);
      }
      *(uint4*)&k0[off] = make_uint4(pk2(hh[0], hh[1]), pk2(hh[2], hh[3]),
                                     pk2(hh[4], hh[5]), pk2(hh[6], hh[7]));
      *(uint4*)&k1[off] = make_uint4(pk2(mm[0], mm[1]), pk2(mm[2], mm[3]),
                                     pk2(mm[4], mm[5]), pk2(mm[6], mm[7]));
      *(uint4*)&k2[off] = make_uint4(pk2(ll[0], ll[1]), pk2(ll[2], ll[3]),
                                     pk2(ll[4], ll[5]), pk2(ll[6], ll[7]));
    }
  } else {
    short vb[4][8];
    #pragma unroll
    for (int i = 0; i < 4; ++i)
      #pragma unroll
      for (int jj = 0; jj < 8; ++jj)
        vb[i][jj] = f2bf(acc[i][jj] + bias[jj]);
    const int jbase = n * 64 + ty * 4;
    #pragma unroll
    for (int jj = 0; jj < 8; ++jj) {
      size_t off = (win * 32 + dh0 + jj) * 256 + jbase;
      *(uint2*)&vt[off] = make_uint2(pk2(vb[0][jj], vb[1][jj]),
                                     pk2(vb[2][jj], vb[3][jj]));
    }
  }
}

// ---------------- Kernel 2: windowed attention (kp-regs + kl-LDS, (256,2)) ----
// One block per window, 256 thr = 4 waves; wave wv owns w-tile wt=wv, loops 4 n.
// R14 lesson: kp+kl both register-resident = 64+ live through PV -> spill.
// Fix: kl (cold lo16 halves, read only post-bisect) lives in LDS klb[wv][j][lane]
// (written once at QK-convert; wave-wide reads are 2-way bank aliasing = free).
// kp[32] (hot: 16 bisect iterations) stays in regs. Peak arch live ~77 < 128.
// K mid+lo stream from global/L2 (LDS fits 80KB/block -> 2 blocks/CU).
__global__ __launch_bounds__(256, 2) void k_attn(
    const float* __restrict__ qh, const short* __restrict__ k0,
    const short* __restrict__ k1, const short* __restrict__ k2,
    const short* __restrict__ vt, float* __restrict__ abar)
{
  __shared__ __align__(16) short ks0s[256][36];   // 18432 B
  __shared__ __align__(16) short vts[32][264];    // 16896 B
  __shared__ __align__(16) short pt[4][16][72];   // 9216 B (per-wave P slab)
  __shared__ uint32_t klb[4][32][64];              // 32768 B (lo16 key halves)
  __shared__ float sal[256];                       // 1024 B
  __shared__ float keepf[256];                     // 1024 B   total 79360 B

  const int win = blockIdx.x;
  const int bh = win >> 6, l = win & 63;
  const int b = bh >> 2, h = bh & 3;
  const int tid = threadIdx.x;
  const int lane = tid & 63, wv = tid >> 6;
  const int g = lane >> 4, p = lane & 15;
  const int wt = wv;                          // 4 waves, 4 w-tiles

  const float* qw = qh + (size_t)win * 8192;
  const short* kw1 = k1 + (size_t)win * 8192;
  const short* kw2 = k2 + (size_t)win * 8192;

  // ---- stage K-hi + V^T into LDS ----
  {
    const uint4* s0 = (const uint4*)(k0 + (size_t)win * 8192);
    const uint4* sv = (const uint4*)(vt + (size_t)win * 8192);
    #pragma unroll
    for (int i = 0; i < 4; ++i) {
      int ci = tid + i * 256;                  // 1024 uint4 per tensor
      *(uint4*)&ks0s[ci >> 2][(ci & 3) * 8] = s0[ci];
      *(uint4*)&vts[ci >> 5][(ci & 31) * 8] = sv[ci];
    }
  }
  // ---- query saliency (FROZEN summation order) ----
  {
    const float4* qg2 = (const float4*)(qw + (size_t)tid * 32);
    float ss = 0.f;
    #pragma unroll
    for (int i = 0; i < 8; ++i) {
      float4 vv = qg2[i];
      ss += vv.x * vv.x + vv.y * vv.y + vv.z * vv.z + vv.w * vv.w;
    }
    sal[tid] = ss;
  }
  __syncthreads();
  if (wv == 0) {                              // exact top-192 saliency (FROZEN)
    float v[4]; bool selq[4];
    #pragma unroll
    for (int s = 0; s < 4; ++s) v[s] = sal[lane + 64 * s];
    topk_sel(v, KEEPQ, lane, selq);
    #pragma unroll
    for (int s = 0; s < 4; ++s) keepf[lane + 64 * s] = selq[s] ? SCALE : 0.0f;
  }
  __syncthreads();

  float4v pacc0 = {0.f, 0.f, 0.f, 0.f};
  float4v pacc1 = {0.f, 0.f, 0.f, 0.f};
  short* ptw = &pt[wv][0][0];                 // [16][72]

  for (int n = 0; n < 4; ++n) {
    const int qbase = n * 64 + wt * 16;
    const float kfp = keepf[qbase + p];       // per-query (col p) keep factor
    const bool kept = (kfp != 0.0f);

    // ---- Q B-fragment: scale+mask then bf16x3 split (FROZEN values) ----
    short8v aq0, aq1, aq2;
    {
      const float* qrow = qw + (size_t)(qbase + p) * 32 + g * 8;
      float4 qa = *(const float4*)qrow;
      float4 qb = *(const float4*)(qrow + 4);
      float qv[8] = {qa.x, qa.y, qa.z, qa.w, qb.x, qb.y, qb.z, qb.w};
      #pragma unroll
      for (int e = 0; e < 8; ++e) {
        short hh, mm, ll;
        split3(qv[e] * kfp, hh, mm, ll);
        aq0[e] = hh; aq1[e] = mm; aq2[e] = ll;
      }
    }

    // ---- QK^T swapped + immediate key conversion (acc transient) ----
    // element e = 4c+r; pair j = e>>1. kp (hi16) -> regs; kl (lo16) -> LDS.
    uint32_t kp[32];
    uint32_t umax32 = 0u, umin32 = 0xFFFFFFFFu;
    #pragma unroll
    for (int c = 0; c < 16; ++c) {
      const short8v b0 = *(const short8v*)&ks0s[c * 16 + p][g * 8];
      const short8v b1 = *(const short8v*)(kw1 + (size_t)(c * 16 + p) * 32 + g * 8);
      const short8v b2 = *(const short8v*)(kw2 + (size_t)(c * 16 + p) * 32 + g * 8);
      float4v a = {0.f, 0.f, 0.f, 0.f};
      a = __builtin_amdgcn_mfma_f32_16x16x32_bf16(b0, aq0, a, 0, 0, 0);
      a = __builtin_amdgcn_mfma_f32_16x16x32_bf16(b0, aq1, a, 0, 0, 0);
      a = __builtin_amdgcn_mfma_f32_16x16x32_bf16(b0, aq2, a, 0, 0, 0);
      a = __builtin_amdgcn_mfma_f32_16x16x32_bf16(b1, aq0, a, 0, 0, 0);
      a = __builtin_amdgcn_mfma_f32_16x16x32_bf16(b1, aq1, a, 0, 0, 0);
      a = __builtin_amdgcn_mfma_f32_16x16x32_bf16(b2, aq0, a, 0, 0, 0);
      const uint32_t f0 = fmap(a[0]), f1 = fmap(a[1]);
      const uint32_t f2_ = fmap(a[2]), f3 = fmap(a[3]);
      umax32 = max(umax32, max(max(f0, f1), max(f2_, f3)));
      umin32 = min(umin32, min(min(f0, f1), min(f2_, f3)));
      kp[2 * c]     = (f0 >> 16) | (f1 & 0xFFFF0000u);
      kp[2 * c + 1] = (f2_ >> 16) | (f3 & 0xFFFF0000u);
      klb[wv][2 * c][lane]     = (f0 & 0xFFFFu) | (f1 << 16);
      klb[wv][2 * c + 1][lane] = (f2_ & 0xFFFFu) | (f3 << 16);
    }
    umax32 = max(umax32, (uint32_t)__shfl_xor((int)umax32, 16));
    umin32 = min(umin32, (uint32_t)__shfl_xor((int)umin32, 16));
    umax32 = max(umax32, (uint32_t)__shfl_xor((int)umax32, 32));
    umin32 = min(umin32, (uint32_t)__shfl_xor((int)umin32, 32));
    const float fm = unmap(umax32);           // canonical exact max (FROZEN value)

    // ---- 16-bit radix bisection on kp: largest T16 with count >= 64 ----
    const uint32_t t16max = umax32 >> 16, t16min = umin32 >> 16;
    uint32_t piv = 0u; int cntge = 256; bool bdone = true;
    if (kept) {
      uint32_t du = t16max ^ t16min;
      if (du == 0u) { piv = t16max; }          // all in one bin -> extraction
      else {
        int sb = 31 - __clz(du);
        piv = t16max & ~((2u << sb) - 1u);     // common prefix, low bits 0
        bdone = false;
      }
    }
    for (int bit = 15; bit >= 0; --bit) {
      if (__all(bdone)) break;
      const uint32_t cand = piv | (1u << bit);
      int cc = 0;
      #pragma unroll
      for (int j = 0; j < 32; ++j) {
        cc += ((kp[j] & 0xFFFFu) >= cand) ? 1 : 0;
        cc += ((kp[j] >> 16) >= cand) ? 1 : 0;
      }
      cc += __shfl_xor(cc, 16);
      cc += __shfl_xor(cc, 32);
      if (!bdone && cc >= 64) {
        piv = cand; cntge = cc;
        if (cc == 64) bdone = true;
      }
    }
    const uint32_t T16 = piv;

    // ---- gt/eq masks at T16 (bit e) ----
    uint64_t gtm = 0ull, eqm = 0ull, picked = 0ull;
    int need = 0;
    if (kept) {
      #pragma unroll
      for (int j = 0; j < 32; ++j) {
        const uint32_t lo = kp[j] & 0xFFFFu, hi = kp[j] >> 16;
        gtm |= (lo > T16) ? (1ull << (2 * j)) : 0ull;
        eqm |= (lo == T16) ? (1ull << (2 * j)) : 0ull;
        gtm |= (hi > T16) ? (1ull << (2 * j + 1)) : 0ull;
        eqm |= (hi == T16) ? (1ull << (2 * j + 1)) : 0ull;
      }
      if (cntge != 64) {
        int gp = (int)__popcll(gtm);
        gp += __shfl_xor(gp, 16);
        gp += __shfl_xor(gp, 32);
        need = 64 - gp;                        // >=1 by radix-select property
      }
    }

    // ---- boundary: pick `need` from eq bin by (kl desc, key idx asc) ----
    // (all eq elements share hi16 == T16, so kl order == full fmap order)
    for (int it = 0; it < 64; ++it) {
      if (__all(need <= 0)) break;
      uint32_t best = 0u; int bk = 256;
      if (need > 0) {
        #pragma unroll
        for (int e = 0; e < 64; ++e) {
          if (((eqm >> e) & 1ull) && !((picked >> e) & 1ull)) {
            const uint32_t w = klb[wv][e >> 1][lane];
            const uint32_t f = (e & 1) ? (w >> 16) : (w & 0xFFFFu);
            const int gk = ((e >> 2) << 4) | (g << 2) | (e & 3);
            if (f > best || (f == best && gk < bk)) { best = f; bk = gk; }
          }
        }
      }
      #pragma unroll
      for (int d = 16; d <= 32; d <<= 1) {
        const uint32_t ov = (uint32_t)__shfl_xor((int)best, d);
        const int oi = __shfl_xor(bk, d);
        if (ov > best || (ov == best && oi < bk)) { best = ov; bk = oi; }
      }
      if (need > 0) {
        if (((bk >> 2) & 3) == g) {
          const int e = ((bk >> 4) << 2) | (bk & 3);
          picked |= (1ull << e);
        }
        need -= 1;
      }
    }
    const uint64_t selm = kept ? (gtm | ((cntge == 64) ? eqm : picked)) : 0ull;

    // exp of element e, reconstructed bit-exactly from (kp, klb); FROZEN values
    auto expe = [&](int e) -> float {
      if (!kept) return (e < 16) ? 0.015625f : 0.0f;  // pruned: first 64 keys
      if (!((selm >> e) & 1ull)) return 0.0f;
      const int j = e >> 1;
      const uint32_t hi16 = (e & 1) ? (kp[j] >> 16) : (kp[j] & 0xFFFFu);
      const uint32_t w = klb[wv][j][lane];
      const uint32_t lo16 = (e & 1) ? (w >> 16) : (w & 0xFFFFu);
      return __expf(unmap((hi16 << 16) | lo16) - fm);
    };

    // ---- esum in FROZEN (e ascending) order ----
    float esum = 0.f;
    #pragma unroll
    for (int j = 0; j < 32; ++j) {
      esum += expe(2 * j);
      esum += expe(2 * j + 1);
    }
    esum += __shfl_xor(esum, 16);
    esum += __shfl_xor(esum, 32);
    const float inv = kept ? (1.0f / esum) : 1.0f;

    // ---- PV: stage P^T per 2-kk block, then MFMA (FROZEN chain order) ----
    #pragma unroll
    for (int t = 0; t < 4; ++t) {
      #pragma unroll
      for (int kq = 0; kq < 2; ++kq) {
        const int kk = 2 * t + kq;
        const int ce = 2 * kk, co = ce + 1;     // c indices; elements 4c+r
        uint2 w0 = make_uint2(
            pk2(f2bf(expe(4 * ce + 0) * inv), f2bf(expe(4 * ce + 1) * inv)),
            pk2(f2bf(expe(4 * ce + 2) * inv), f2bf(expe(4 * ce + 3) * inv)));
        uint2 w1 = make_uint2(
            pk2(f2bf(expe(4 * co + 0) * inv), f2bf(expe(4 * co + 1) * inv)),
            pk2(f2bf(expe(4 * co + 2) * inv), f2bf(expe(4 * co + 3) * inv)));
        *(uint2*)&ptw[p * 72 + kq * 32 + 4 * g] = w0;
        *(uint2*)&ptw[p * 72 + kq * 32 + 16 + 4 * g] = w1;
      }
      // cross-lane visibility of this wave's writes (no HIP-level dependency)
      asm volatile("s_waitcnt lgkmcnt(0)" ::: "memory");
      __builtin_amdgcn_sched_barrier(0);
      #pragma unroll
      for (int kq = 0; kq < 2; ++kq) {
        const int kk = 2 * t + kq;
        short8v pa = *(const short8v*)&ptw[p * 72 + kq * 32 + 8 * g];
        short8v v0 = *(const short8v*)&vts[p][kk * 32 + 8 * g];
        short8v v1 = *(const short8v*)&vts[16 + p][kk * 32 + 8 * g];
        pacc0 = __builtin_amdgcn_mfma_f32_16x16x32_bf16(pa, v0, pacc0, 0, 0, 0);
        pacc1 = __builtin_amdgcn_mfma_f32_16x16x32_bf16(pa, v1, pacc1, 0, 0, 0);
      }
    }
  }

  // ---- write abar = mean over n (each wave owns its w-tile; no reduction) ----
  #pragma unroll
  for (int rr = 0; rr < 4; ++rr) {
    const int w = wt * 16 + g * 4 + rr;
    size_t o = ((size_t)(b * 64 + l) * 64 + w) * 128 + h * 32;
    abar[o + p] = pacc0[rr] * 0.25f;
    abar[o + 16 + p] = pacc1[rr] * 0.25f;
  }
}

// ---------------- Kernel 3: final projection (FROZEN) ----------------
__global__ __launch_bounds__(256) void k_proj(
    const float* __restrict__ abar, const float* __restrict__ W,
    const float* __restrict__ bi, float* __restrict__ out)
{
  __shared__ float xs[64 * 132];
  const int tile = blockIdx.x;
  const int tid = threadIdx.x;
  const float4* xg = (const float4*)(abar + (size_t)tile * 64 * 128);
  #pragma unroll
  for (int i = 0; i < 8; ++i) {
    int idx = tid + i * 256;
    int r = idx >> 5, c = (idx & 31) * 4;
    *(float4*)&xs[r * 132 + c] = xg[idx];
  }
  __syncthreads();

  const int ty = tid >> 4, tx = tid & 15;
  float acc[4][8];
  #pragma unroll
  for (int i = 0; i < 4; ++i)
    #pragma unroll
    for (int j = 0; j < 8; ++j) acc[i][j] = 0.f;

  #pragma unroll 2
  for (int kk = 0; kk < 128; kk += 4) {
    float aa[4][4];
    #pragma unroll
    for (int i = 0; i < 4; ++i)
      *(float4*)&aa[i][0] = *(const float4*)&xs[(ty * 4 + i) * 132 + kk];
    #pragma unroll
    for (int t2 = 0; t2 < 4; ++t2) {
      const float4 w0 = *(const float4*)&W[(kk + t2) * 128 + tx * 8];
      const float4 w1 = *(const float4*)&W[(kk + t2) * 128 + tx * 8 + 4];
      #pragma unroll
      for (int i = 0; i < 4; ++i) {
        acc[i][0] = fmaf(aa[i][t2], w0.x, acc[i][0]);
        acc[i][1] = fmaf(aa[i][t2], w0.y, acc[i][1]);
        acc[i][2] = fmaf(aa[i][t2], w0.z, acc[i][2]);
        acc[i][3] = fmaf(aa[i][t2], w0.w, acc[i][3]);
        acc[i][4] = fmaf(aa[i][t2], w1.x, acc[i][4]);
        acc[i][5] = fmaf(aa[i][t2], w1.y, acc[i][5]);
        acc[i][6] = fmaf(aa[i][t2], w1.z, acc[i][6]);
        acc[i][7] = fmaf(aa[i][t2], w1.w, acc[i][7]);
      }
    }
  }
  #pragma unroll
  for (int i = 0; i < 4; ++i) {
    size_t row = (size_t)tile * 64 + ty * 4 + i;
    float4 o0 = make_float4(acc[i][0] + bi[tx * 8 + 0], acc[i][1] + bi[tx * 8 + 1],
                            acc[i][2] + bi[tx * 8 + 2], acc[i][3] + bi[tx * 8 + 3]);
    float4 o1 = make_float4(acc[i][4] + bi[tx * 8 + 4], acc[i][5] + bi[tx * 8 + 5],
                            acc[i][6] + bi[tx * 8 + 6], acc[i][7] + bi[tx * 8 + 7]);
    *(float4*)&out[row * 128 + tx * 8] = o0;
    *(float4*)&out[row * 128 + tx * 8 + 4] = o1;
  }
}

extern "C" void kernel_launch(void* const* d_in, const int* in_sizes, int n_in,
                              void* d_out, int out_size, void* d_ws, size_t ws_size,
                              hipStream_t stream) {
  (void)in_sizes; (void)n_in; (void)out_size; (void)ws_size;
  const float* xq   = (const float*)d_in[0];
  const float* xk   = (const float*)d_in[1];
  const float* xv   = (const float*)d_in[2];
  const float* gq   = (const float*)d_in[3];
  const float* beq  = (const float*)d_in[4];
  const float* gk   = (const float*)d_in[5];
  const float* bek  = (const float*)d_in[6];
  const float* gv   = (const float*)d_in[7];
  const float* bev  = (const float*)d_in[8];
  const float* wq   = (const float*)d_in[9];
  const float* biq  = (const float*)d_in[10];
  const float* wk   = (const float*)d_in[11];
  const float* bik  = (const float*)d_in[12];
  const float* wv   = (const float*)d_in[13];
  const float* biv  = (const float*)d_in[14];
  const float* wpr  = (const float*)d_in[15];
  const float* bpr  = (const float*)d_in[16];

  // ws layout (109,051,904 B total == proven footprint):
  char* ws = (char*)d_ws;
  float* qh  = (float*)(ws);                       // 33,554,432 B
  short* k0  = (short*)(ws + 33554432);            // 16,777,216 B
  short* k1  = (short*)(ws + 50331648);            // 16,777,216 B
  short* k2  = (short*)(ws + 67108864);            // 16,777,216 B
  short* vt  = (short*)(ws + 83886080);            // 16,777,216 B
  float* abar = (float*)(ws + 100663296);          //  8,388,608 B

  k_lnproj<<<dim3(1024, 3), 256, 0, stream>>>(xq, xk, xv, gq, beq, gk, bek, gv, bev,
                                              wq, biq, wk, bik, wv, biv,
                                              qh, k0, k1, k2, vt);
  k_attn<<<1024, 256, 0, stream>>>(qh, k0, k1, k2, vt, abar);
  k_proj<<<256, 256, 0, stream>>>(abar, wpr, bpr, (float*)d_out);
}

// Round 16
// 374.698 us; speedup vs baseline: 1.1969x; 1.1969x over previous
//
#include <hip/hip_runtime.h>
#include <stdint.h>

// CrossWinAttention: b=4 n=4 x=y=8 w1=w2=8 d=128, H=4 Dh=32, L=64, NW=256, BH=16.
#define LN_EPS 1e-5f
#define SCALE 0.17677669529663687f   // 32^-0.5
#define KEEPQ 192

typedef __attribute__((ext_vector_type(8))) short short8v;   // 8 bf16
typedef __attribute__((ext_vector_type(4))) float float4v;

__device__ __forceinline__ short f2bf(float x) {             // RNE f32->bf16
  uint32_t u = __float_as_uint(x);
  uint32_t r = (u + 0x7FFFu + ((u >> 16) & 1u)) >> 16;
  return (short)r;
}
__device__ __forceinline__ float bf2f(short s) {
  return __uint_as_float(((uint32_t)(uint16_t)s) << 16);
}
__device__ __forceinline__ uint32_t pk2(short a, short b) {
  return (uint32_t)(uint16_t)a | ((uint32_t)(uint16_t)b << 16);
}
__device__ __forceinline__ void split3(float x, short &h, short &m, short &l) {
  h = f2bf(x); float r1 = x - bf2f(h);
  m = f2bf(r1); float r2 = r1 - bf2f(m);
  l = f2bf(r2);
}
__device__ __forceinline__ uint32_t fmap(float x) {          // order-preserving map
  uint32_t bb = __float_as_uint(x);
  if ((bb & 0x7FFFFFFFu) == 0u) bb = 0u;                     // -0 -> +0
  return (bb & 0x80000000u) ? ~bb : (bb | 0x80000000u);
}
__device__ __forceinline__ float unmap(uint32_t m) {         // inverse of fmap
  uint32_t b = (m & 0x80000000u) ? (m & 0x7FFFFFFFu) : ~m;
  return __uint_as_float(b);
}

// Exact top-k over 256 values, 4 per lane (element index = lane + 64*s).
// Tie-break: smaller index wins. All 64 lanes must participate.
__device__ __forceinline__ void topk_sel(const float v[4], int k, int lane, bool sel[4]) {
  uint32_t u[4];
  #pragma unroll
  for (int s = 0; s < 4; ++s) u[s] = fmap(v[s]);
  uint32_t prefix = 0u;
  bool exact = false;
  for (int bit = 31; bit >= 0; --bit) {
    uint32_t cand = prefix | (1u << bit);
    int c = 0;
    #pragma unroll
    for (int s = 0; s < 4; ++s) c += __popcll(__ballot(u[s] >= cand));
    if (c >= k) {
      prefix = cand;
      if (c == k) { exact = true; break; }
    }
  }
  if (exact) {
    #pragma unroll
    for (int s = 0; s < 4; ++s) sel[s] = (u[s] >= prefix);
    return;
  }
  const uint32_t T = prefix;
  int gt = 0;
  unsigned long long eb[4];
  #pragma unroll
  for (int s = 0; s < 4; ++s) {
    gt += __popcll(__ballot(u[s] > T));
    eb[s] = __ballot(u[s] == T);
  }
  const int need = k - gt;
  const unsigned long long lm = (1ull << lane) - 1ull;
  int base = 0;
  #pragma unroll
  for (int s = 0; s < 4; ++s) {
    int before = base + __popcll(eb[s] & lm);
    sel[s] = (u[s] > T) || ((u[s] == T) && (before < need));
    base += __popcll(eb[s]);
  }
}

// ---------------- Kernel 1: LN + QKV projection (FROZEN numerics) ----------------
__global__ __launch_bounds__(256) void k_lnproj(
    const float* __restrict__ xq, const float* __restrict__ xk, const float* __restrict__ xv,
    const float* __restrict__ gq, const float* __restrict__ beq,
    const float* __restrict__ gk, const float* __restrict__ bek,
    const float* __restrict__ gv, const float* __restrict__ bev,
    const float* __restrict__ wq, const float* __restrict__ biq,
    const float* __restrict__ wk, const float* __restrict__ bik,
    const float* __restrict__ wv, const float* __restrict__ biv,
    float* __restrict__ qh, short* __restrict__ k0, short* __restrict__ k1,
    short* __restrict__ k2, short* __restrict__ vt)
{
  __shared__ float xs[64 * 132];
  const int tile = blockIdx.x;
  const int t = blockIdx.y;
  const float* x  = (t == 0) ? xq : (t == 1) ? xk : xv;
  const float* g  = (t == 0) ? gq : (t == 1) ? gk : gv;
  const float* be = (t == 0) ? beq : (t == 1) ? bek : bev;
  const float* W  = (t == 0) ? wq : (t == 1) ? wk : wv;
  const float* bi = (t == 0) ? biq : (t == 1) ? bik : biv;
  const int tid = threadIdx.x;

  const float4* xg = (const float4*)(x + (size_t)tile * 64 * 128);
  #pragma unroll
  for (int i = 0; i < 8; ++i) {
    int idx = tid + i * 256;
    int r = idx >> 5;
    int c = (idx & 31) * 4;
    *(float4*)&xs[r * 132 + c] = xg[idx];
  }
  __syncthreads();

  {
    int r = tid >> 2, p = tid & 3;
    float s = 0.f, sq = 0.f;
    #pragma unroll
    for (int c = 0; c < 32; ++c) {
      float vv = xs[r * 132 + p * 32 + c];
      s += vv; sq += vv * vv;
    }
    s += __shfl_xor(s, 1, 64); sq += __shfl_xor(sq, 1, 64);
    s += __shfl_xor(s, 2, 64); sq += __shfl_xor(sq, 2, 64);
    float mean = s * (1.0f / 128.0f);
    float var = sq * (1.0f / 128.0f) - mean * mean;
    float rstd = rsqrtf(var + LN_EPS);
    #pragma unroll
    for (int c = 0; c < 32; ++c) {
      int cc = p * 32 + c;
      xs[r * 132 + cc] = (xs[r * 132 + cc] - mean) * rstd * g[cc] + be[cc];
    }
  }
  __syncthreads();

  const int ty = tid >> 4, tx = tid & 15;
  float acc[4][8];
  #pragma unroll
  for (int i = 0; i < 4; ++i)
    #pragma unroll
    for (int j = 0; j < 8; ++j) acc[i][j] = 0.f;

  #pragma unroll 2
  for (int kk = 0; kk < 128; kk += 4) {
    float aa[4][4];
    #pragma unroll
    for (int i = 0; i < 4; ++i)
      *(float4*)&aa[i][0] = *(const float4*)&xs[(ty * 4 + i) * 132 + kk];
    #pragma unroll
    for (int t2 = 0; t2 < 4; ++t2) {
      const float4 w0 = *(const float4*)&W[(kk + t2) * 128 + tx * 8];
      const float4 w1 = *(const float4*)&W[(kk + t2) * 128 + tx * 8 + 4];
      #pragma unroll
      for (int i = 0; i < 4; ++i) {
        acc[i][0] = fmaf(aa[i][t2], w0.x, acc[i][0]);
        acc[i][1] = fmaf(aa[i][t2], w0.y, acc[i][1]);
        acc[i][2] = fmaf(aa[i][t2], w0.z, acc[i][2]);
        acc[i][3] = fmaf(aa[i][t2], w0.w, acc[i][3]);
        acc[i][4] = fmaf(aa[i][t2], w1.x, acc[i][4]);
        acc[i][5] = fmaf(aa[i][t2], w1.y, acc[i][5]);
        acc[i][6] = fmaf(aa[i][t2], w1.z, acc[i][6]);
        acc[i][7] = fmaf(aa[i][t2], w1.w, acc[i][7]);
      }
    }
  }

  float bias[8];
  #pragma unroll
  for (int j = 0; j < 8; ++j) bias[j] = bi[tx * 8 + j];
  const int b  = tile >> 8;
  const int n  = (tile >> 6) & 3;
  const int l  = ((tile >> 3) & 7) * 8 + (tile & 7);
  const int h  = tx >> 2;
  const int dh0 = (tx & 3) * 8;
  const size_t win = (size_t)(b * 4 + h) * 64 + l;

  if (t == 0) {
    #pragma unroll
    for (int i = 0; i < 4; ++i) {
      int j = n * 64 + ty * 4 + i;
      size_t off = (win * 256 + j) * 32 + dh0;
      float4 o0 = make_float4(acc[i][0] + bias[0], acc[i][1] + bias[1],
                              acc[i][2] + bias[2], acc[i][3] + bias[3]);
      float4 o1 = make_float4(acc[i][4] + bias[4], acc[i][5] + bias[5],
                              acc[i][6] + bias[6], acc[i][7] + bias[7]);
      *(float4*)&qh[off] = o0;
      *(float4*)&qh[off + 4] = o1;
    }
  } else if (t == 1) {
    #pragma unroll
    for (int i = 0; i < 4; ++i) {
      int j = n * 64 + ty * 4 + i;
      size_t off = (win * 256 + j) * 32 + dh0;
      short hh[8], mm[8], ll[8];
      #pragma unroll
      for (int jj = 0; jj < 8; ++jj) {
        float o = acc[i][jj] + bias[jj];
        split3(o, hh[jj], mm[jj], ll[jj]);
      }
      *(uint4*)&k0[off] = make_uint4(pk2(hh[0], hh[1]), pk2(hh[2], hh[3]),
                                     pk2(hh[4], hh[5]), pk2(hh[6], hh[7]));
      *(uint4*)&k1[off] = make_uint4(pk2(mm[0], mm[1]), pk2(mm[2], mm[3]),
                                     pk2(mm[4], mm[5]), pk2(mm[6], mm[7]));
      *(uint4*)&k2[off] = make_uint4(pk2(ll[0], ll[1]), pk2(ll[2], ll[3]),
                                     pk2(ll[4], ll[5]), pk2(ll[6], ll[7]));
    }
  } else {
    short vb[4][8];
    #pragma unroll
    for (int i = 0; i < 4; ++i)
      #pragma unroll
      for (int jj = 0; jj < 8; ++jj)
        vb[i][jj] = f2bf(acc[i][jj] + bias[jj]);
    const int jbase = n * 64 + ty * 4;
    #pragma unroll
    for (int jj = 0; jj < 8; ++jj) {
      size_t off = (win * 32 + dh0 + jj) * 256 + jbase;
      *(uint2*)&vt[off] = make_uint2(pk2(vb[0][jj], vb[1][jj]),
                                     pk2(vb[2][jj], vb[3][jj]));
    }
  }
}

// ---------------- Kernel 2: windowed attention (float bisect + sched fence) ----
// One block per window, 256 thr = 4 waves; wave wv owns w-tile wt=wv, loops 4 n.
// R15 lesson: spill magnitude tracked the number of GLOBAL-load streams in the
// fully-unrolled QK loop, not named-array liveness -> the pre-RA scheduler
// hoists in-flight global loads (up to 16 iters x 8 regs). Fix: keep R11's
// structure (best measured, 230 us) and fence the scheduler every 4th c-iter
// with sched_barrier(0), bounding in-flight loads to ~32 regs. Scheduling-only
// change: bit-identical results to R11.
__global__ __launch_bounds__(256, 2) void k_attn(
    const float* __restrict__ qh, const short* __restrict__ k0,
    const short* __restrict__ k1, const short* __restrict__ k2,
    const short* __restrict__ vt, float* __restrict__ abar)
{
  __shared__ __align__(16) short ks0s[256][36];   // 18432 B
  __shared__ __align__(16) short ks1s[256][36];   // 18432 B
  __shared__ __align__(16) short vts[32][264];    // 16896 B
  __shared__ __align__(16) short pt[4][16][72];   // 9216 B (per-wave P slab)
  __shared__ float sal[256];                       // 1024 B
  __shared__ float keepf[256];                     // 1024 B   total 65024 B

  const int win = blockIdx.x;
  const int bh = win >> 6, l = win & 63;
  const int b = bh >> 2, h = bh & 3;
  const int tid = threadIdx.x;
  const int lane = tid & 63, wv = tid >> 6;
  const int g = lane >> 4, p = lane & 15;
  const int wt = wv;                          // 4 waves, 4 w-tiles

  const float* qw = qh + (size_t)win * 8192;
  const short* kw2 = k2 + (size_t)win * 8192;

  // ---- stage K hi/mid + V^T into LDS ----
  {
    const uint4* s0 = (const uint4*)(k0 + (size_t)win * 8192);
    const uint4* s1 = (const uint4*)(k1 + (size_t)win * 8192);
    const uint4* sv = (const uint4*)(vt + (size_t)win * 8192);
    #pragma unroll
    for (int i = 0; i < 4; ++i) {
      int ci = tid + i * 256;                  // 1024 uint4 per tensor
      *(uint4*)&ks0s[ci >> 2][(ci & 3) * 8] = s0[ci];
      *(uint4*)&ks1s[ci >> 2][(ci & 3) * 8] = s1[ci];
      *(uint4*)&vts[ci >> 5][(ci & 31) * 8] = sv[ci];
    }
  }
  // ---- query saliency (FROZEN summation order) ----
  {
    const float4* qg2 = (const float4*)(qw + (size_t)tid * 32);
    float ss = 0.f;
    #pragma unroll
    for (int i = 0; i < 8; ++i) {
      float4 vv = qg2[i];
      ss += vv.x * vv.x + vv.y * vv.y + vv.z * vv.z + vv.w * vv.w;
    }
    sal[tid] = ss;
  }
  __syncthreads();
  if (wv == 0) {                              // exact top-192 saliency (FROZEN)
    float v[4]; bool selq[4];
    #pragma unroll
    for (int s = 0; s < 4; ++s) v[s] = sal[lane + 64 * s];
    topk_sel(v, KEEPQ, lane, selq);
    #pragma unroll
    for (int s = 0; s < 4; ++s) keepf[lane + 64 * s] = selq[s] ? SCALE : 0.0f;
  }
  __syncthreads();

  float4v pacc0 = {0.f, 0.f, 0.f, 0.f};
  float4v pacc1 = {0.f, 0.f, 0.f, 0.f};
  short* ptw = &pt[wv][0][0];                 // [16][72]

  for (int n = 0; n < 4; ++n) {
    const int qbase = n * 64 + wt * 16;
    const float kfp = keepf[qbase + p];       // per-query (col p) keep factor
    const bool kept = (kfp != 0.0f);

    // ---- Q B-fragment: scale+mask then bf16x3 split (FROZEN values) ----
    short8v aq0, aq1, aq2;
    {
      const float* qrow = qw + (size_t)(qbase + p) * 32 + g * 8;
      float4 qa = *(const float4*)qrow;
      float4 qb = *(const float4*)(qrow + 4);
      float qv[8] = {qa.x, qa.y, qa.z, qa.w, qb.x, qb.y, qb.z, qb.w};
      #pragma unroll
      for (int e = 0; e < 8; ++e) {
        short hh, mm, ll;
        split3(qv[e] * kfp, hh, mm, ll);
        aq0[e] = hh; aq1[e] = mm; aq2[e] = ll;
      }
    }

    // ---- QK^T swapped: acc[c][r] = S[key 16c+4g+r][query qbase+p]; FROZEN ----
    // sched_barrier every 4th iter caps global-load hoisting (~32 in-flight regs).
    float4v acc[16];
    #pragma unroll
    for (int c = 0; c < 16; ++c) {
      const short8v b0 = *(const short8v*)&ks0s[c * 16 + p][g * 8];
      const short8v b1 = *(const short8v*)&ks1s[c * 16 + p][g * 8];
      const short8v b2 = *(const short8v*)(kw2 + (size_t)(c * 16 + p) * 32 + g * 8);
      float4v a = {0.f, 0.f, 0.f, 0.f};
      a = __builtin_amdgcn_mfma_f32_16x16x32_bf16(b0, aq0, a, 0, 0, 0);
      a = __builtin_amdgcn_mfma_f32_16x16x32_bf16(b0, aq1, a, 0, 0, 0);
      a = __builtin_amdgcn_mfma_f32_16x16x32_bf16(b0, aq2, a, 0, 0, 0);
      a = __builtin_amdgcn_mfma_f32_16x16x32_bf16(b1, aq0, a, 0, 0, 0);
      a = __builtin_amdgcn_mfma_f32_16x16x32_bf16(b1, aq1, a, 0, 0, 0);
      a = __builtin_amdgcn_mfma_f32_16x16x32_bf16(b2, aq0, a, 0, 0, 0);
      acc[c] = a;
      if ((c & 3) == 3) __builtin_amdgcn_sched_barrier(0);
    }

    // ---- float max/min reduce over the query's 256 keys ----
    float fmx = acc[0][0], fmn = acc[0][0];
    #pragma unroll
    for (int c = 0; c < 16; ++c) {
      #pragma unroll
      for (int r = 0; r < 4; ++r) {
        fmx = fmaxf(fmx, acc[c][r]);
        fmn = fminf(fmn, acc[c][r]);
      }
    }
    fmx = fmaxf(fmx, __shfl_xor(fmx, 16));
    fmn = fminf(fmn, __shfl_xor(fmn, 16));
    fmx = fmaxf(fmx, __shfl_xor(fmx, 32));
    fmn = fminf(fmn, __shfl_xor(fmn, 32));
    const uint32_t umaxu = fmap(fmx), uminu = fmap(fmn);
    const float fm = unmap(umaxu);            // canonical (+0) exact max

    // ---- exact top-64 threshold: bisection with FLOAT compares ----
    uint32_t piv = 0u; int cnt = 256; int sb = -1; bool bdone = true;
    if (kept) {
      uint32_t du = umaxu ^ uminu;
      if (du != 0u) {
        sb = 31 - __clz(du);
        piv = (sb >= 31) ? 0u : (umaxu & (0xFFFFFFFFu << (sb + 1)));
        bdone = false;
      } else { piv = umaxu; }                 // all equal -> tie path
    }
    for (int bit = 31; bit >= 0; --bit) {
      if (__all(bdone)) break;
      const uint32_t cand = piv | (1u << bit);
      const float tf = unmap(cand);
      int cc = 0;
      #pragma unroll
      for (int c = 0; c < 16; ++c) {
        #pragma unroll
        for (int r = 0; r < 4; ++r) cc += (acc[c][r] >= tf) ? 1 : 0;
      }
      cc += __shfl_xor(cc, 16);
      cc += __shfl_xor(cc, 32);
      if (!bdone && bit <= sb && cc >= 64) {
        piv = cand; cnt = cc;
        if (cc == 64) bdone = true;
      }
    }
    const float Tf = unmap(piv);

    // ---- selection mask (bit 4c+r), exact tie-break by key index ----
    uint64_t selm = 0ull;
    if (kept) {
      if (cnt == 64) {
        #pragma unroll
        for (int c = 0; c < 16; ++c)
          #pragma unroll
          for (int r = 0; r < 4; ++r)
            selm |= (acc[c][r] >= Tf) ? (1ull << (4 * c + r)) : 0ull;
      } else {
        // rare: ties at T (T is an attained value -> float ==/> consistent).
        int gtc = 0;
        #pragma unroll
        for (int c = 0; c < 16; ++c)
          #pragma unroll
          for (int r = 0; r < 4; ++r) gtc += (acc[c][r] > Tf) ? 1 : 0;
        gtc += __shfl_xor(gtc, 16);
        gtc += __shfl_xor(gtc, 32);
        const int need = 64 - gtc;
        uint64_t em = 0ull;
        #pragma unroll
        for (int c = 0; c < 16; ++c)
          #pragma unroll
          for (int r = 0; r < 4; ++r)
            em |= (acc[c][r] == Tf) ? (1ull << (4 * c + r)) : 0ull;
        uint64_t emA = __shfl_xor((unsigned long long)em, 16);
        uint64_t emB = __shfl_xor((unsigned long long)em, 32);
        uint64_t emC = __shfl_xor((unsigned long long)emA, 32);
        uint64_t M0 = (g == 0) ? em : ((g == 1) ? emA : ((g == 2) ? emB : emC));
        uint64_t M1 = (g == 1) ? em : ((g == 0) ? emA : ((g == 3) ? emB : emC));
        uint64_t M2 = (g == 2) ? em : ((g == 3) ? emA : ((g == 0) ? emB : emC));
        uint64_t M3 = (g == 3) ? em : ((g == 2) ? emA : ((g == 1) ? emB : emC));
        int pref = 0;
        #pragma unroll
        for (int c = 0; c < 16; ++c) {
          int n0 = (int)((M0 >> (4 * c)) & 15ull);
          int n1 = (int)((M1 >> (4 * c)) & 15ull);
          int n2 = (int)((M2 >> (4 * c)) & 15ull);
          int n3 = (int)((M3 >> (4 * c)) & 15ull);
          int gs = ((g > 0) ? __popc(n0) : 0) + ((g > 1) ? __popc(n1) : 0)
                 + ((g > 2) ? __popc(n2) : 0);
          int on = (int)((em >> (4 * c)) & 15ull);
          #pragma unroll
          for (int r = 0; r < 4; ++r) {
            bool s2;
            if (acc[c][r] > Tf) s2 = true;
            else if (acc[c][r] == Tf) {
              int before = pref + gs + __popc(on & ((1 << r) - 1));
              s2 = (before < need);
            } else s2 = false;
            selm |= s2 ? (1ull << (4 * c + r)) : 0ull;
          }
          pref += __popc(n0) + __popc(n1) + __popc(n2) + __popc(n3);
        }
      }
    }

    // ---- e = exp(S - fm) on selected; OVERWRITE acc in place; esum (FROZEN) ----
    float esum = 0.f;
    #pragma unroll
    for (int c = 0; c < 16; ++c) {
      #pragma unroll
      for (int r = 0; r < 4; ++r) {
        float e;
        if (kept)
          e = ((selm >> (4 * c + r)) & 1ull) ? __expf(acc[c][r] - fm) : 0.0f;
        else
          e = (c < 4) ? 0.015625f : 0.0f;    // pruned: uniform 1/64 over first 64 keys
        acc[c][r] = e;
        esum += e;
      }
    }
    esum += __shfl_xor(esum, 16);
    esum += __shfl_xor(esum, 32);
    const float inv = kept ? (1.0f / esum) : 1.0f;

    // ---- PV: stage P^T per 2-kk block, then MFMA (FROZEN chain order) ----
    #pragma unroll
    for (int t = 0; t < 4; ++t) {
      #pragma unroll
      for (int kq = 0; kq < 2; ++kq) {
        const int kk = 2 * t + kq;
        const int ce = 2 * kk, co = ce + 1;
        uint2 w0 = make_uint2(pk2(f2bf(acc[ce][0] * inv), f2bf(acc[ce][1] * inv)),
                              pk2(f2bf(acc[ce][2] * inv), f2bf(acc[ce][3] * inv)));
        uint2 w1 = make_uint2(pk2(f2bf(acc[co][0] * inv), f2bf(acc[co][1] * inv)),
                              pk2(f2bf(acc[co][2] * inv), f2bf(acc[co][3] * inv)));
        *(uint2*)&ptw[p * 72 + kq * 32 + 4 * g] = w0;
        *(uint2*)&ptw[p * 72 + kq * 32 + 16 + 4 * g] = w1;
      }
      // cross-lane visibility of this wave's writes (no HIP-level dependency)
      asm volatile("s_waitcnt lgkmcnt(0)" ::: "memory");
      __builtin_amdgcn_sched_barrier(0);
      #pragma unroll
      for (int kq = 0; kq < 2; ++kq) {
        const int kk = 2 * t + kq;
        short8v pa = *(const short8v*)&ptw[p * 72 + kq * 32 + 8 * g];
        short8v v0 = *(const short8v*)&vts[p][kk * 32 + 8 * g];
        short8v v1 = *(const short8v*)&vts[16 + p][kk * 32 + 8 * g];
        pacc0 = __builtin_amdgcn_mfma_f32_16x16x32_bf16(pa, v0, pacc0, 0, 0, 0);
        pacc1 = __builtin_amdgcn_mfma_f32_16x16x32_bf16(pa, v1, pacc1, 0, 0, 0);
      }
    }
  }

  // ---- write abar = mean over n (each wave owns its w-tile; no reduction) ----
  #pragma unroll
  for (int rr = 0; rr < 4; ++rr) {
    const int w = wt * 16 + g * 4 + rr;
    size_t o = ((size_t)(b * 64 + l) * 64 + w) * 128 + h * 32;
    abar[o + p] = pacc0[rr] * 0.25f;
    abar[o + 16 + p] = pacc1[rr] * 0.25f;
  }
}

// ---------------- Kernel 3: final projection (FROZEN) ----------------
__global__ __launch_bounds__(256) void k_proj(
    const float* __restrict__ abar, const float* __restrict__ W,
    const float* __restrict__ bi, float* __restrict__ out)
{
  __shared__ float xs[64 * 132];
  const int tile = blockIdx.x;
  const int tid = threadIdx.x;
  const float4* xg = (const float4*)(abar + (size_t)tile * 64 * 128);
  #pragma unroll
  for (int i = 0; i < 8; ++i) {
    int idx = tid + i * 256;
    int r = idx >> 5, c = (idx & 31) * 4;
    *(float4*)&xs[r * 132 + c] = xg[idx];
  }
  __syncthreads();

  const int ty = tid >> 4, tx = tid & 15;
  float acc[4][8];
  #pragma unroll
  for (int i = 0; i < 4; ++i)
    #pragma unroll
    for (int j = 0; j < 8; ++j) acc[i][j] = 0.f;

  #pragma unroll 2
  for (int kk = 0; kk < 128; kk += 4) {
    float aa[4][4];
    #pragma unroll
    for (int i = 0; i < 4; ++i)
      *(float4*)&aa[i][0] = *(const float4*)&xs[(ty * 4 + i) * 132 + kk];
    #pragma unroll
    for (int t2 = 0; t2 < 4; ++t2) {
      const float4 w0 = *(const float4*)&W[(kk + t2) * 128 + tx * 8];
      const float4 w1 = *(const float4*)&W[(kk + t2) * 128 + tx * 8 + 4];
      #pragma unroll
      for (int i = 0; i < 4; ++i) {
        acc[i][0] = fmaf(aa[i][t2], w0.x, acc[i][0]);
        acc[i][1] = fmaf(aa[i][t2], w0.y, acc[i][1]);
        acc[i][2] = fmaf(aa[i][t2], w0.z, acc[i][2]);
        acc[i][3] = fmaf(aa[i][t2], w0.w, acc[i][3]);
        acc[i][4] = fmaf(aa[i][t2], w1.x, acc[i][4]);
        acc[i][5] = fmaf(aa[i][t2], w1.y, acc[i][5]);
        acc[i][6] = fmaf(aa[i][t2], w1.z, acc[i][6]);
        acc[i][7] = fmaf(aa[i][t2], w1.w, acc[i][7]);
      }
    }
  }
  #pragma unroll
  for (int i = 0; i < 4; ++i) {
    size_t row = (size_t)tile * 64 + ty * 4 + i;
    float4 o0 = make_float4(acc[i][0] + bi[tx * 8 + 0], acc[i][1] + bi[tx * 8 + 1],
                            acc[i][2] + bi[tx * 8 + 2], acc[i][3] + bi[tx * 8 + 3]);
    float4 o1 = make_float4(acc[i][4] + bi[tx * 8 + 4], acc[i][5] + bi[tx * 8 + 5],
                            acc[i][6] + bi[tx * 8 + 6], acc[i][7] + bi[tx * 8 + 7]);
    *(float4*)&out[row * 128 + tx * 8] = o0;
    *(float4*)&out[row * 128 + tx * 8 + 4] = o1;
  }
}

extern "C" void kernel_launch(void* const* d_in, const int* in_sizes, int n_in,
                              void* d_out, int out_size, void* d_ws, size_t ws_size,
                              hipStream_t stream) {
  (void)in_sizes; (void)n_in; (void)out_size; (void)ws_size;
  const float* xq   = (const float*)d_in[0];
  const float* xk   = (const float*)d_in[1];
  const float* xv   = (const float*)d_in[2];
  const float* gq   = (const float*)d_in[3];
  const float* beq  = (const float*)d_in[4];
  const float* gk   = (const float*)d_in[5];
  const float* bek  = (const float*)d_in[6];
  const float* gv   = (const float*)d_in[7];
  const float* bev  = (const float*)d_in[8];
  const float* wq   = (const float*)d_in[9];
  const float* biq  = (const float*)d_in[10];
  const float* wk   = (const float*)d_in[11];
  const float* bik  = (const float*)d_in[12];
  const float* wv   = (const float*)d_in[13];
  const float* biv  = (const float*)d_in[14];
  const float* wpr  = (const float*)d_in[15];
  const float* bpr  = (const float*)d_in[16];

  // ws layout (109,051,904 B total == proven footprint):
  char* ws = (char*)d_ws;
  float* qh  = (float*)(ws);                       // 33,554,432 B
  short* k0  = (short*)(ws + 33554432);            // 16,777,216 B
  short* k1  = (short*)(ws + 50331648);            // 16,777,216 B
  short* k2  = (short*)(ws + 67108864);            // 16,777,216 B
  short* vt  = (short*)(ws + 83886080);            // 16,777,216 B
  float* abar = (float*)(ws + 100663296);          //  8,388,608 B

  k_lnproj<<<dim3(1024, 3), 256, 0, stream>>>(xq, xk, xv, gq, beq, gk, bek, gv, bev,
                                              wq, biq, wk, bik, wv, biv,
                                              qh, k0, k1, k2, vt);
  k_attn<<<1024, 256, 0, stream>>>(qh, k0, k1, k2, vt, abar);
  k_proj<<<256, 256, 0, stream>>>(abar, wpr, bpr, (float*)d_out);
}

// Round 17
// 358.115 us; speedup vs baseline: 1.2523x; 1.0463x over previous
//
#include <hip/hip_runtime.h>
#include <stdint.h>

// CrossWinAttention: b=4 n=4 x=y=8 w1=w2=8 d=128, H=4 Dh=32, L=64, NW=256, BH=16.
#define LN_EPS 1e-5f
#define SCALE 0.17677669529663687f   // 32^-0.5
#define KEEPQ 192

typedef __attribute__((ext_vector_type(8))) short short8v;   // 8 bf16
typedef __attribute__((ext_vector_type(4))) float float4v;

__device__ __forceinline__ short f2bf(float x) {             // RNE f32->bf16
  uint32_t u = __float_as_uint(x);
  uint32_t r = (u + 0x7FFFu + ((u >> 16) & 1u)) >> 16;
  return (short)r;
}
__device__ __forceinline__ float bf2f(short s) {
  return __uint_as_float(((uint32_t)(uint16_t)s) << 16);
}
__device__ __forceinline__ uint32_t pk2(short a, short b) {
  return (uint32_t)(uint16_t)a | ((uint32_t)(uint16_t)b << 16);
}
__device__ __forceinline__ void split3(float x, short &h, short &m, short &l) {
  h = f2bf(x); float r1 = x - bf2f(h);
  m = f2bf(r1); float r2 = r1 - bf2f(m);
  l = f2bf(r2);
}
__device__ __forceinline__ uint32_t fmap(float x) {          // order-preserving map
  uint32_t bb = __float_as_uint(x);
  if ((bb & 0x7FFFFFFFu) == 0u) bb = 0u;                     // -0 -> +0
  return (bb & 0x80000000u) ? ~bb : (bb | 0x80000000u);
}
__device__ __forceinline__ float unmap(uint32_t m) {         // inverse of fmap
  uint32_t b = (m & 0x80000000u) ? (m & 0x7FFFFFFFu) : ~m;
  return __uint_as_float(b);
}

// Exact top-k over 256 values, 4 per lane (element index = lane + 64*s).
// Tie-break: smaller index wins. All 64 lanes must participate.
__device__ __forceinline__ void topk_sel(const float v[4], int k, int lane, bool sel[4]) {
  uint32_t u[4];
  #pragma unroll
  for (int s = 0; s < 4; ++s) u[s] = fmap(v[s]);
  uint32_t prefix = 0u;
  bool exact = false;
  for (int bit = 31; bit >= 0; --bit) {
    uint32_t cand = prefix | (1u << bit);
    int c = 0;
    #pragma unroll
    for (int s = 0; s < 4; ++s) c += __popcll(__ballot(u[s] >= cand));
    if (c >= k) {
      prefix = cand;
      if (c == k) { exact = true; break; }
    }
  }
  if (exact) {
    #pragma unroll
    for (int s = 0; s < 4; ++s) sel[s] = (u[s] >= prefix);
    return;
  }
  const uint32_t T = prefix;
  int gt = 0;
  unsigned long long eb[4];
  #pragma unroll
  for (int s = 0; s < 4; ++s) {
    gt += __popcll(__ballot(u[s] > T));
    eb[s] = __ballot(u[s] == T);
  }
  const int need = k - gt;
  const unsigned long long lm = (1ull << lane) - 1ull;
  int base = 0;
  #pragma unroll
  for (int s = 0; s < 4; ++s) {
    int before = base + __popcll(eb[s] & lm);
    sel[s] = (u[s] > T) || ((u[s] == T) && (before < need));
    base += __popcll(eb[s]);
  }
}

// ---------------- Kernel 1: LN + QKV projection (FROZEN numerics) ----------------
__global__ __launch_bounds__(256) void k_lnproj(
    const float* __restrict__ xq, const float* __restrict__ xk, const float* __restrict__ xv,
    const float* __restrict__ gq, const float* __restrict__ beq,
    const float* __restrict__ gk, const float* __restrict__ bek,
    const float* __restrict__ gv, const float* __restrict__ bev,
    const float* __restrict__ wq, const float* __restrict__ biq,
    const float* __restrict__ wk, const float* __restrict__ bik,
    const float* __restrict__ wv, const float* __restrict__ biv,
    float* __restrict__ qh, short* __restrict__ k0, short* __restrict__ k1,
    short* __restrict__ k2, short* __restrict__ vt)
{
  __shared__ float xs[64 * 132];
  const int tile = blockIdx.x;
  const int t = blockIdx.y;
  const float* x  = (t == 0) ? xq : (t == 1) ? xk : xv;
  const float* g  = (t == 0) ? gq : (t == 1) ? gk : gv;
  const float* be = (t == 0) ? beq : (t == 1) ? bek : bev;
  const float* W  = (t == 0) ? wq : (t == 1) ? wk : wv;
  const float* bi = (t == 0) ? biq : (t == 1) ? bik : biv;
  const int tid = threadIdx.x;

  const float4* xg = (const float4*)(x + (size_t)tile * 64 * 128);
  #pragma unroll
  for (int i = 0; i < 8; ++i) {
    int idx = tid + i * 256;
    int r = idx >> 5;
    int c = (idx & 31) * 4;
    *(float4*)&xs[r * 132 + c] = xg[idx];
  }
  __syncthreads();

  {
    int r = tid >> 2, p = tid & 3;
    float s = 0.f, sq = 0.f;
    #pragma unroll
    for (int c = 0; c < 32; ++c) {
      float vv = xs[r * 132 + p * 32 + c];
      s += vv; sq += vv * vv;
    }
    s += __shfl_xor(s, 1, 64); sq += __shfl_xor(sq, 1, 64);
    s += __shfl_xor(s, 2, 64); sq += __shfl_xor(sq, 2, 64);
    float mean = s * (1.0f / 128.0f);
    float var = sq * (1.0f / 128.0f) - mean * mean;
    float rstd = rsqrtf(var + LN_EPS);
    #pragma unroll
    for (int c = 0; c < 32; ++c) {
      int cc = p * 32 + c;
      xs[r * 132 + cc] = (xs[r * 132 + cc] - mean) * rstd * g[cc] + be[cc];
    }
  }
  __syncthreads();

  const int ty = tid >> 4, tx = tid & 15;
  float acc[4][8];
  #pragma unroll
  for (int i = 0; i < 4; ++i)
    #pragma unroll
    for (int j = 0; j < 8; ++j) acc[i][j] = 0.f;

  #pragma unroll 2
  for (int kk = 0; kk < 128; kk += 4) {
    float aa[4][4];
    #pragma unroll
    for (int i = 0; i < 4; ++i)
      *(float4*)&aa[i][0] = *(const float4*)&xs[(ty * 4 + i) * 132 + kk];
    #pragma unroll
    for (int t2 = 0; t2 < 4; ++t2) {
      const float4 w0 = *(const float4*)&W[(kk + t2) * 128 + tx * 8];
      const float4 w1 = *(const float4*)&W[(kk + t2) * 128 + tx * 8 + 4];
      #pragma unroll
      for (int i = 0; i < 4; ++i) {
        acc[i][0] = fmaf(aa[i][t2], w0.x, acc[i][0]);
        acc[i][1] = fmaf(aa[i][t2], w0.y, acc[i][1]);
        acc[i][2] = fmaf(aa[i][t2], w0.z, acc[i][2]);
        acc[i][3] = fmaf(aa[i][t2], w0.w, acc[i][3]);
        acc[i][4] = fmaf(aa[i][t2], w1.x, acc[i][4]);
        acc[i][5] = fmaf(aa[i][t2], w1.y, acc[i][5]);
        acc[i][6] = fmaf(aa[i][t2], w1.z, acc[i][6]);
        acc[i][7] = fmaf(aa[i][t2], w1.w, acc[i][7]);
      }
    }
  }

  float bias[8];
  #pragma unroll
  for (int j = 0; j < 8; ++j) bias[j] = bi[tx * 8 + j];
  const int b  = tile >> 8;
  const int n  = (tile >> 6) & 3;
  const int l  = ((tile >> 3) & 7) * 8 + (tile & 7);
  const int h  = tx >> 2;
  const int dh0 = (tx & 3) * 8;
  const size_t win = (size_t)(b * 4 + h) * 64 + l;

  if (t == 0) {
    #pragma unroll
    for (int i = 0; i < 4; ++i) {
      int j = n * 64 + ty * 4 + i;
      size_t off = (win * 256 + j) * 32 + dh0;
      float4 o0 = make_float4(acc[i][0] + bias[0], acc[i][1] + bias[1],
                              acc[i][2] + bias[2], acc[i][3] + bias[3]);
      float4 o1 = make_float4(acc[i][4] + bias[4], acc[i][5] + bias[5],
                              acc[i][6] + bias[6], acc[i][7] + bias[7]);
      *(float4*)&qh[off] = o0;
      *(float4*)&qh[off + 4] = o1;
    }
  } else if (t == 1) {
    #pragma unroll
    for (int i = 0; i < 4; ++i) {
      int j = n * 64 + ty * 4 + i;
      size_t off = (win * 256 + j) * 32 + dh0;
      short hh[8], mm[8], ll[8];
      #pragma unroll
      for (int jj = 0; jj < 8; ++jj) {
        float o = acc[i][jj] + bias[jj];
        split3(o, hh[jj], mm[jj], ll[jj]);
      }
      *(uint4*)&k0[off] = make_uint4(pk2(hh[0], hh[1]), pk2(hh[2], hh[3]),
                                     pk2(hh[4], hh[5]), pk2(hh[6], hh[7]));
      *(uint4*)&k1[off] = make_uint4(pk2(mm[0], mm[1]), pk2(mm[2], mm[3]),
                                     pk2(mm[4], mm[5]), pk2(mm[6], mm[7]));
      *(uint4*)&k2[off] = make_uint4(pk2(ll[0], ll[1]), pk2(ll[2], ll[3]),
                                     pk2(ll[4], ll[5]), pk2(ll[6], ll[7]));
    }
  } else {
    short vb[4][8];
    #pragma unroll
    for (int i = 0; i < 4; ++i)
      #pragma unroll
      for (int jj = 0; jj < 8; ++jj)
        vb[i][jj] = f2bf(acc[i][jj] + bias[jj]);
    const int jbase = n * 64 + ty * 4;
    #pragma unroll
    for (int jj = 0; jj < 8; ++jj) {
      size_t off = (win * 32 + dh0 + jj) * 256 + jbase;
      *(uint2*)&vt[off] = make_uint2(pk2(vb[0][jj], vb[1][jj]),
                                     pk2(vb[2][jj], vb[3][jj]));
    }
  }
}

// ---------------- Kernel 2: windowed attention (float bisect, lean tie path) ---
// One block per window, 256 thr = 4 waves; wave wv owns w-tile wt=wv, loops 4 n.
// R16 lesson: the scheduler fence was neutral; the ~22-dword spill is static
// allocation pressure. Largest trimmable chunk: the tie path materialized 8
// 64-bit masks (em/emA/emB/emC/M0-M3 = 16 regs). Replaced with a per-c
// incremental scan (on/cn + 3 partner shuffles + running pref) computing the
// SAME integer `before` in the same (c,g,r)=ascending-key order -> selm
// bit-identical. Partner lanes (g^1,g^2,g^3 of same query p) always take the
// same branch, so shuffles under divergence are safe.
__global__ __launch_bounds__(256, 2) void k_attn(
    const float* __restrict__ qh, const short* __restrict__ k0,
    const short* __restrict__ k1, const short* __restrict__ k2,
    const short* __restrict__ vt, float* __restrict__ abar)
{
  __shared__ __align__(16) short ks0s[256][36];   // 18432 B
  __shared__ __align__(16) short ks1s[256][36];   // 18432 B
  __shared__ __align__(16) short vts[32][264];    // 16896 B
  __shared__ __align__(16) short pt[4][16][72];   // 9216 B (per-wave P slab)
  __shared__ float sal[256];                       // 1024 B
  __shared__ float keepf[256];                     // 1024 B   total 65024 B

  const int win = blockIdx.x;
  const int bh = win >> 6, l = win & 63;
  const int b = bh >> 2, h = bh & 3;
  const int tid = threadIdx.x;
  const int lane = tid & 63, wv = tid >> 6;
  const int g = lane >> 4, p = lane & 15;
  const int wt = wv;                          // 4 waves, 4 w-tiles

  const float* qw = qh + (size_t)win * 8192;
  const short* kw2 = k2 + (size_t)win * 8192;

  // ---- stage K hi/mid + V^T into LDS ----
  {
    const uint4* s0 = (const uint4*)(k0 + (size_t)win * 8192);
    const uint4* s1 = (const uint4*)(k1 + (size_t)win * 8192);
    const uint4* sv = (const uint4*)(vt + (size_t)win * 8192);
    #pragma unroll
    for (int i = 0; i < 4; ++i) {
      int ci = tid + i * 256;                  // 1024 uint4 per tensor
      *(uint4*)&ks0s[ci >> 2][(ci & 3) * 8] = s0[ci];
      *(uint4*)&ks1s[ci >> 2][(ci & 3) * 8] = s1[ci];
      *(uint4*)&vts[ci >> 5][(ci & 31) * 8] = sv[ci];
    }
  }
  // ---- query saliency (FROZEN summation order) ----
  {
    const float4* qg2 = (const float4*)(qw + (size_t)tid * 32);
    float ss = 0.f;
    #pragma unroll
    for (int i = 0; i < 8; ++i) {
      float4 vv = qg2[i];
      ss += vv.x * vv.x + vv.y * vv.y + vv.z * vv.z + vv.w * vv.w;
    }
    sal[tid] = ss;
  }
  __syncthreads();
  if (wv == 0) {                              // exact top-192 saliency (FROZEN)
    float v[4]; bool selq[4];
    #pragma unroll
    for (int s = 0; s < 4; ++s) v[s] = sal[lane + 64 * s];
    topk_sel(v, KEEPQ, lane, selq);
    #pragma unroll
    for (int s = 0; s < 4; ++s) keepf[lane + 64 * s] = selq[s] ? SCALE : 0.0f;
  }
  __syncthreads();

  float4v pacc0 = {0.f, 0.f, 0.f, 0.f};
  float4v pacc1 = {0.f, 0.f, 0.f, 0.f};
  short* ptw = &pt[wv][0][0];                 // [16][72]

  for (int n = 0; n < 4; ++n) {
    const int qbase = n * 64 + wt * 16;
    const float kfp = keepf[qbase + p];       // per-query (col p) keep factor
    const bool kept = (kfp != 0.0f);

    // ---- Q B-fragment: scale+mask then bf16x3 split (FROZEN values) ----
    short8v aq0, aq1, aq2;
    {
      const float* qrow = qw + (size_t)(qbase + p) * 32 + g * 8;
      float4 qa = *(const float4*)qrow;
      float4 qb = *(const float4*)(qrow + 4);
      float qv[8] = {qa.x, qa.y, qa.z, qa.w, qb.x, qb.y, qb.z, qb.w};
      #pragma unroll
      for (int e = 0; e < 8; ++e) {
        short hh, mm, ll;
        split3(qv[e] * kfp, hh, mm, ll);
        aq0[e] = hh; aq1[e] = mm; aq2[e] = ll;
      }
    }

    // ---- QK^T swapped: acc[c][r] = S[key 16c+4g+r][query qbase+p]; FROZEN ----
    float4v acc[16];
    #pragma unroll
    for (int c = 0; c < 16; ++c) {
      const short8v b0 = *(const short8v*)&ks0s[c * 16 + p][g * 8];
      const short8v b1 = *(const short8v*)&ks1s[c * 16 + p][g * 8];
      const short8v b2 = *(const short8v*)(kw2 + (size_t)(c * 16 + p) * 32 + g * 8);
      float4v a = {0.f, 0.f, 0.f, 0.f};
      a = __builtin_amdgcn_mfma_f32_16x16x32_bf16(b0, aq0, a, 0, 0, 0);
      a = __builtin_amdgcn_mfma_f32_16x16x32_bf16(b0, aq1, a, 0, 0, 0);
      a = __builtin_amdgcn_mfma_f32_16x16x32_bf16(b0, aq2, a, 0, 0, 0);
      a = __builtin_amdgcn_mfma_f32_16x16x32_bf16(b1, aq0, a, 0, 0, 0);
      a = __builtin_amdgcn_mfma_f32_16x16x32_bf16(b1, aq1, a, 0, 0, 0);
      a = __builtin_amdgcn_mfma_f32_16x16x32_bf16(b2, aq0, a, 0, 0, 0);
      acc[c] = a;
      if ((c & 3) == 3) __builtin_amdgcn_sched_barrier(0);
    }

    // ---- float max/min reduce over the query's 256 keys ----
    float fmx = acc[0][0], fmn = acc[0][0];
    #pragma unroll
    for (int c = 0; c < 16; ++c) {
      #pragma unroll
      for (int r = 0; r < 4; ++r) {
        fmx = fmaxf(fmx, acc[c][r]);
        fmn = fminf(fmn, acc[c][r]);
      }
    }
    fmx = fmaxf(fmx, __shfl_xor(fmx, 16));
    fmn = fminf(fmn, __shfl_xor(fmn, 16));
    fmx = fmaxf(fmx, __shfl_xor(fmx, 32));
    fmn = fminf(fmn, __shfl_xor(fmn, 32));
    const uint32_t umaxu = fmap(fmx), uminu = fmap(fmn);
    const float fm = unmap(umaxu);            // canonical (+0) exact max

    // ---- exact top-64 threshold: bisection with FLOAT compares ----
    uint32_t piv = 0u; int cnt = 256; int sb = -1; bool bdone = true;
    if (kept) {
      uint32_t du = umaxu ^ uminu;
      if (du != 0u) {
        sb = 31 - __clz(du);
        piv = (sb >= 31) ? 0u : (umaxu & (0xFFFFFFFFu << (sb + 1)));
        bdone = false;
      } else { piv = umaxu; }                 // all equal -> tie path
    }
    for (int bit = 31; bit >= 0; --bit) {
      if (__all(bdone)) break;
      const uint32_t cand = piv | (1u << bit);
      const float tf = unmap(cand);
      int cc = 0;
      #pragma unroll
      for (int c = 0; c < 16; ++c) {
        #pragma unroll
        for (int r = 0; r < 4; ++r) cc += (acc[c][r] >= tf) ? 1 : 0;
      }
      cc += __shfl_xor(cc, 16);
      cc += __shfl_xor(cc, 32);
      if (!bdone && bit <= sb && cc >= 64) {
        piv = cand; cnt = cc;
        if (cc == 64) bdone = true;
      }
    }
    const float Tf = unmap(piv);

    // ---- selection mask (bit 4c+r), exact tie-break by key index ----
    uint64_t selm = 0ull;
    if (kept) {
      if (cnt == 64) {
        #pragma unroll
        for (int c = 0; c < 16; ++c)
          #pragma unroll
          for (int r = 0; r < 4; ++r)
            selm |= (acc[c][r] >= Tf) ? (1ull << (4 * c + r)) : 0ull;
      } else {
        // rare: ties at Tf. Register-light per-c incremental scan.
        // Partners (g^1,g^2,g^3 of same query) take the same branch -> shuffles safe.
        int gtc = 0;
        #pragma unroll
        for (int c = 0; c < 16; ++c)
          #pragma unroll
          for (int r = 0; r < 4; ++r) gtc += (acc[c][r] > Tf) ? 1 : 0;
        gtc += __shfl_xor(gtc, 16);
        gtc += __shfl_xor(gtc, 32);
        const int need = 64 - gtc;
        int pref = 0;                          // eq count in key blocks c' < c
        #pragma unroll
        for (int c = 0; c < 16; ++c) {
          int on = 0;                          // eq nibble for this lane's 4 keys
          #pragma unroll
          for (int r = 0; r < 4; ++r) on |= (acc[c][r] == Tf) ? (1 << r) : 0;
          const int cn = __popc(on);
          const int cnA = __shfl_xor(cn, 16);  // group g^1
          const int cnB = __shfl_xor(cn, 32);  // group g^2
          const int cnC = __shfl_xor(cnA, 32); // group g^3
          const int gs = (((g ^ 1) < g) ? cnA : 0)
                       + (((g ^ 2) < g) ? cnB : 0)
                       + (((g ^ 3) < g) ? cnC : 0);
          #pragma unroll
          for (int r = 0; r < 4; ++r) {
            bool s2;
            if (acc[c][r] > Tf) s2 = true;
            else if (acc[c][r] == Tf) {
              int before = pref + gs + __popc(on & ((1 << r) - 1));
              s2 = (before < need);
            } else s2 = false;
            selm |= s2 ? (1ull << (4 * c + r)) : 0ull;
          }
          pref += cn + cnA + cnB + cnC;
        }
      }
    }

    // ---- e = exp(S - fm) on selected; OVERWRITE acc in place; esum (FROZEN) ----
    float esum = 0.f;
    #pragma unroll
    for (int c = 0; c < 16; ++c) {
      #pragma unroll
      for (int r = 0; r < 4; ++r) {
        float e;
        if (kept)
          e = ((selm >> (4 * c + r)) & 1ull) ? __expf(acc[c][r] - fm) : 0.0f;
        else
          e = (c < 4) ? 0.015625f : 0.0f;    // pruned: uniform 1/64 over first 64 keys
        acc[c][r] = e;
        esum += e;
      }
    }
    esum += __shfl_xor(esum, 16);
    esum += __shfl_xor(esum, 32);
    const float inv = kept ? (1.0f / esum) : 1.0f;

    // ---- PV: stage P^T per 2-kk block, then MFMA (FROZEN chain order) ----
    #pragma unroll
    for (int t = 0; t < 4; ++t) {
      #pragma unroll
      for (int kq = 0; kq < 2; ++kq) {
        const int kk = 2 * t + kq;
        const int ce = 2 * kk, co = ce + 1;
        uint2 w0 = make_uint2(pk2(f2bf(acc[ce][0] * inv), f2bf(acc[ce][1] * inv)),
                              pk2(f2bf(acc[ce][2] * inv), f2bf(acc[ce][3] * inv)));
        uint2 w1 = make_uint2(pk2(f2bf(acc[co][0] * inv), f2bf(acc[co][1] * inv)),
                              pk2(f2bf(acc[co][2] * inv), f2bf(acc[co][3] * inv)));
        *(uint2*)&ptw[p * 72 + kq * 32 + 4 * g] = w0;
        *(uint2*)&ptw[p * 72 + kq * 32 + 16 + 4 * g] = w1;
      }
      // cross-lane visibility of this wave's writes (no HIP-level dependency)
      asm volatile("s_waitcnt lgkmcnt(0)" ::: "memory");
      __builtin_amdgcn_sched_barrier(0);
      #pragma unroll
      for (int kq = 0; kq < 2; ++kq) {
        const int kk = 2 * t + kq;
        short8v pa = *(const short8v*)&ptw[p * 72 + kq * 32 + 8 * g];
        short8v v0 = *(const short8v*)&vts[p][kk * 32 + 8 * g];
        short8v v1 = *(const short8v*)&vts[16 + p][kk * 32 + 8 * g];
        pacc0 = __builtin_amdgcn_mfma_f32_16x16x32_bf16(pa, v0, pacc0, 0, 0, 0);
        pacc1 = __builtin_amdgcn_mfma_f32_16x16x32_bf16(pa, v1, pacc1, 0, 0, 0);
      }
    }
  }

  // ---- write abar = mean over n (each wave owns its w-tile; no reduction) ----
  #pragma unroll
  for (int rr = 0; rr < 4; ++rr) {
    const int w = wt * 16 + g * 4 + rr;
    size_t o = ((size_t)(b * 64 + l) * 64 + w) * 128 + h * 32;
    abar[o + p] = pacc0[rr] * 0.25f;
    abar[o + 16 + p] = pacc1[rr] * 0.25f;
  }
}

// ---------------- Kernel 3: final projection (FROZEN) ----------------
__global__ __launch_bounds__(256) void k_proj(
    const float* __restrict__ abar, const float* __restrict__ W,
    const float* __restrict__ bi, float* __restrict__ out)
{
  __shared__ float xs[64 * 132];
  const int tile = blockIdx.x;
  const int tid = threadIdx.x;
  const float4* xg = (const float4*)(abar + (size_t)tile * 64 * 128);
  #pragma unroll
  for (int i = 0; i < 8; ++i) {
    int idx = tid + i * 256;
    int r = idx >> 5, c = (idx & 31) * 4;
    *(float4*)&xs[r * 132 + c] = xg[idx];
  }
  __syncthreads();

  const int ty = tid >> 4, tx = tid & 15;
  float acc[4][8];
  #pragma unroll
  for (int i = 0; i < 4; ++i)
    #pragma unroll
    for (int j = 0; j < 8; ++j) acc[i][j] = 0.f;

  #pragma unroll 2
  for (int kk = 0; kk < 128; kk += 4) {
    float aa[4][4];
    #pragma unroll
    for (int i = 0; i < 4; ++i)
      *(float4*)&aa[i][0] = *(const float4*)&xs[(ty * 4 + i) * 132 + kk];
    #pragma unroll
    for (int t2 = 0; t2 < 4; ++t2) {
      const float4 w0 = *(const float4*)&W[(kk + t2) * 128 + tx * 8];
      const float4 w1 = *(const float4*)&W[(kk + t2) * 128 + tx * 8 + 4];
      #pragma unroll
      for (int i = 0; i < 4; ++i) {
        acc[i][0] = fmaf(aa[i][t2], w0.x, acc[i][0]);
        acc[i][1] = fmaf(aa[i][t2], w0.y, acc[i][1]);
        acc[i][2] = fmaf(aa[i][t2], w0.z, acc[i][2]);
        acc[i][3] = fmaf(aa[i][t2], w0.w, acc[i][3]);
        acc[i][4] = fmaf(aa[i][t2], w1.x, acc[i][4]);
        acc[i][5] = fmaf(aa[i][t2], w1.y, acc[i][5]);
        acc[i][6] = fmaf(aa[i][t2], w1.z, acc[i][6]);
        acc[i][7] = fmaf(aa[i][t2], w1.w, acc[i][7]);
      }
    }
  }
  #pragma unroll
  for (int i = 0; i < 4; ++i) {
    size_t row = (size_t)tile * 64 + ty * 4 + i;
    float4 o0 = make_float4(acc[i][0] + bi[tx * 8 + 0], acc[i][1] + bi[tx * 8 + 1],
                            acc[i][2] + bi[tx * 8 + 2], acc[i][3] + bi[tx * 8 + 3]);
    float4 o1 = make_float4(acc[i][4] + bi[tx * 8 + 4], acc[i][5] + bi[tx * 8 + 5],
                            acc[i][6] + bi[tx * 8 + 6], acc[i][7] + bi[tx * 8 + 7]);
    *(float4*)&out[row * 128 + tx * 8] = o0;
    *(float4*)&out[row * 128 + tx * 8 + 4] = o1;
  }
}

extern "C" void kernel_launch(void* const* d_in, const int* in_sizes, int n_in,
                              void* d_out, int out_size, void* d_ws, size_t ws_size,
                              hipStream_t stream) {
  (void)in_sizes; (void)n_in; (void)out_size; (void)ws_size;
  const float* xq   = (const float*)d_in[0];
  const float* xk   = (const float*)d_in[1];
  const float* xv   = (const float*)d_in[2];
  const float* gq   = (const float*)d_in[3];
  const float* beq  = (const float*)d_in[4];
  const float* gk   = (const float*)d_in[5];
  const float* bek  = (const float*)d_in[6];
  const float* gv   = (const float*)d_in[7];
  const float* bev  = (const float*)d_in[8];
  const float* wq   = (const float*)d_in[9];
  const float* biq  = (const float*)d_in[10];
  const float* wk   = (const float*)d_in[11];
  const float* bik  = (const float*)d_in[12];
  const float* wv   = (const float*)d_in[13];
  const float* biv  = (const float*)d_in[14];
  const float* wpr  = (const float*)d_in[15];
  const float* bpr  = (const float*)d_in[16];

  // ws layout (109,051,904 B total == proven footprint):
  char* ws = (char*)d_ws;
  float* qh  = (float*)(ws);                       // 33,554,432 B
  short* k0  = (short*)(ws + 33554432);            // 16,777,216 B
  short* k1  = (short*)(ws + 50331648);            // 16,777,216 B
  short* k2  = (short*)(ws + 67108864);            // 16,777,216 B
  short* vt  = (short*)(ws + 83886080);            // 16,777,216 B
  float* abar = (float*)(ws + 100663296);          //  8,388,608 B

  k_lnproj<<<dim3(1024, 3), 256, 0, stream>>>(xq, xk, xv, gq, beq, gk, bek, gv, bev,
                                              wq, biq, wk, bik, wv, biv,
                                              qh, k0, k1, k2, vt);
  k_attn<<<1024, 256, 0, stream>>>(qh, k0, k1, k2, vt, abar);
  k_proj<<<256, 256, 0, stream>>>(abar, wpr, bpr, (float*)d_out);
}

// Round 18
// 317.573 us; speedup vs baseline: 1.4122x; 1.1277x over previous
//
#include <hip/hip_runtime.h>
#include <stdint.h>

// CrossWinAttention: b=4 n=4 x=y=8 w1=w2=8 d=128, H=4 Dh=32, L=64, NW=256, BH=16.
#define LN_EPS 1e-5f
#define SCALE 0.17677669529663687f   // 32^-0.5
#define KEEPQ 192

typedef __attribute__((ext_vector_type(8))) short short8v;   // 8 bf16
typedef __attribute__((ext_vector_type(4))) float float4v;

__device__ __forceinline__ short f2bf(float x) {             // RNE f32->bf16
  uint32_t u = __float_as_uint(x);
  uint32_t r = (u + 0x7FFFu + ((u >> 16) & 1u)) >> 16;
  return (short)r;
}
__device__ __forceinline__ float bf2f(short s) {
  return __uint_as_float(((uint32_t)(uint16_t)s) << 16);
}
__device__ __forceinline__ uint32_t pk2(short a, short b) {
  return (uint32_t)(uint16_t)a | ((uint32_t)(uint16_t)b << 16);
}
__device__ __forceinline__ void split3(float x, short &h, short &m, short &l) {
  h = f2bf(x); float r1 = x - bf2f(h);
  m = f2bf(r1); float r2 = r1 - bf2f(m);
  l = f2bf(r2);
}
__device__ __forceinline__ uint32_t fmap(float x) {          // order-preserving map
  uint32_t bb = __float_as_uint(x);
  if ((bb & 0x7FFFFFFFu) == 0u) bb = 0u;                     // -0 -> +0
  return (bb & 0x80000000u) ? ~bb : (bb | 0x80000000u);
}
__device__ __forceinline__ float unmap(uint32_t m) {         // inverse of fmap
  uint32_t b = (m & 0x80000000u) ? (m & 0x7FFFFFFFu) : ~m;
  return __uint_as_float(b);
}

// Exact top-k over 256 values, 4 per lane (element index = lane + 64*s).
// Tie-break: smaller index wins. All 64 lanes must participate.
__device__ __forceinline__ void topk_sel(const float v[4], int k, int lane, bool sel[4]) {
  uint32_t u[4];
  #pragma unroll
  for (int s = 0; s < 4; ++s) u[s] = fmap(v[s]);
  uint32_t prefix = 0u;
  bool exact = false;
  for (int bit = 31; bit >= 0; --bit) {
    uint32_t cand = prefix | (1u << bit);
    int c = 0;
    #pragma unroll
    for (int s = 0; s < 4; ++s) c += __popcll(__ballot(u[s] >= cand));
    if (c >= k) {
      prefix = cand;
      if (c == k) { exact = true; break; }
    }
  }
  if (exact) {
    #pragma unroll
    for (int s = 0; s < 4; ++s) sel[s] = (u[s] >= prefix);
    return;
  }
  const uint32_t T = prefix;
  int gt = 0;
  unsigned long long eb[4];
  #pragma unroll
  for (int s = 0; s < 4; ++s) {
    gt += __popcll(__ballot(u[s] > T));
    eb[s] = __ballot(u[s] == T);
  }
  const int need = k - gt;
  const unsigned long long lm = (1ull << lane) - 1ull;
  int base = 0;
  #pragma unroll
  for (int s = 0; s < 4; ++s) {
    int before = base + __popcll(eb[s] & lm);
    sel[s] = (u[s] > T) || ((u[s] == T) && (before < need));
    base += __popcll(eb[s]);
  }
}

// ---------------- Kernel 1: LN + QKV projection (FROZEN numerics) ----------------
__global__ __launch_bounds__(256) void k_lnproj(
    const float* __restrict__ xq, const float* __restrict__ xk, const float* __restrict__ xv,
    const float* __restrict__ gq, const float* __restrict__ beq,
    const float* __restrict__ gk, const float* __restrict__ bek,
    const float* __restrict__ gv, const float* __restrict__ bev,
    const float* __restrict__ wq, const float* __restrict__ biq,
    const float* __restrict__ wk, const float* __restrict__ bik,
    const float* __restrict__ wv, const float* __restrict__ biv,
    float* __restrict__ qh, short* __restrict__ k0, short* __restrict__ k1,
    short* __restrict__ k2, short* __restrict__ vt)
{
  __shared__ float xs[64 * 132];
  const int tile = blockIdx.x;
  const int t = blockIdx.y;
  const float* x  = (t == 0) ? xq : (t == 1) ? xk : xv;
  const float* g  = (t == 0) ? gq : (t == 1) ? gk : gv;
  const float* be = (t == 0) ? beq : (t == 1) ? bek : bev;
  const float* W  = (t == 0) ? wq : (t == 1) ? wk : wv;
  const float* bi = (t == 0) ? biq : (t == 1) ? bik : biv;
  const int tid = threadIdx.x;

  const float4* xg = (const float4*)(x + (size_t)tile * 64 * 128);
  #pragma unroll
  for (int i = 0; i < 8; ++i) {
    int idx = tid + i * 256;
    int r = idx >> 5;
    int c = (idx & 31) * 4;
    *(float4*)&xs[r * 132 + c] = xg[idx];
  }
  __syncthreads();

  {
    int r = tid >> 2, p = tid & 3;
    float s = 0.f, sq = 0.f;
    #pragma unroll
    for (int c = 0; c < 32; ++c) {
      float vv = xs[r * 132 + p * 32 + c];
      s += vv; sq += vv * vv;
    }
    s += __shfl_xor(s, 1, 64); sq += __shfl_xor(sq, 1, 64);
    s += __shfl_xor(s, 2, 64); sq += __shfl_xor(sq, 2, 64);
    float mean = s * (1.0f / 128.0f);
    float var = sq * (1.0f / 128.0f) - mean * mean;
    float rstd = rsqrtf(var + LN_EPS);
    #pragma unroll
    for (int c = 0; c < 32; ++c) {
      int cc = p * 32 + c;
      xs[r * 132 + cc] = (xs[r * 132 + cc] - mean) * rstd * g[cc] + be[cc];
    }
  }
  __syncthreads();

  const int ty = tid >> 4, tx = tid & 15;
  float acc[4][8];
  #pragma unroll
  for (int i = 0; i < 4; ++i)
    #pragma unroll
    for (int j = 0; j < 8; ++j) acc[i][j] = 0.f;

  #pragma unroll 2
  for (int kk = 0; kk < 128; kk += 4) {
    float aa[4][4];
    #pragma unroll
    for (int i = 0; i < 4; ++i)
      *(float4*)&aa[i][0] = *(const float4*)&xs[(ty * 4 + i) * 132 + kk];
    #pragma unroll
    for (int t2 = 0; t2 < 4; ++t2) {
      const float4 w0 = *(const float4*)&W[(kk + t2) * 128 + tx * 8];
      const float4 w1 = *(const float4*)&W[(kk + t2) * 128 + tx * 8 + 4];
      #pragma unroll
      for (int i = 0; i < 4; ++i) {
        acc[i][0] = fmaf(aa[i][t2], w0.x, acc[i][0]);
        acc[i][1] = fmaf(aa[i][t2], w0.y, acc[i][1]);
        acc[i][2] = fmaf(aa[i][t2], w0.z, acc[i][2]);
        acc[i][3] = fmaf(aa[i][t2], w0.w, acc[i][3]);
        acc[i][4] = fmaf(aa[i][t2], w1.x, acc[i][4]);
        acc[i][5] = fmaf(aa[i][t2], w1.y, acc[i][5]);
        acc[i][6] = fmaf(aa[i][t2], w1.z, acc[i][6]);
        acc[i][7] = fmaf(aa[i][t2], w1.w, acc[i][7]);
      }
    }
  }

  float bias[8];
  #pragma unroll
  for (int j = 0; j < 8; ++j) bias[j] = bi[tx * 8 + j];
  const int b  = tile >> 8;
  const int n  = (tile >> 6) & 3;
  const int l  = ((tile >> 3) & 7) * 8 + (tile & 7);
  const int h  = tx >> 2;
  const int dh0 = (tx & 3) * 8;
  const size_t win = (size_t)(b * 4 + h) * 64 + l;

  if (t == 0) {
    #pragma unroll
    for (int i = 0; i < 4; ++i) {
      int j = n * 64 + ty * 4 + i;
      size_t off = (win * 256 + j) * 32 + dh0;
      float4 o0 = make_float4(acc[i][0] + bias[0], acc[i][1] + bias[1],
                              acc[i][2] + bias[2], acc[i][3] + bias[3]);
      float4 o1 = make_float4(acc[i][4] + bias[4], acc[i][5] + bias[5],
                              acc[i][6] + bias[6], acc[i][7] + bias[7]);
      *(float4*)&qh[off] = o0;
      *(float4*)&qh[off + 4] = o1;
    }
  } else if (t == 1) {
    #pragma unroll
    for (int i = 0; i < 4; ++i) {
      int j = n * 64 + ty * 4 + i;
      size_t off = (win * 256 + j) * 32 + dh0;
      short hh[8], mm[8], ll[8];
      #pragma unroll
      for (int jj = 0; jj < 8; ++jj) {
        float o = acc[i][jj] + bias[jj];
        split3(o, hh[jj], mm[jj], ll[jj]);
      }
      *(uint4*)&k0[off] = make_uint4(pk2(hh[0], hh[1]), pk2(hh[2], hh[3]),
                                     pk2(hh[4], hh[5]), pk2(hh[6], hh[7]));
      *(uint4*)&k1[off] = make_uint4(pk2(mm[0], mm[1]), pk2(mm[2], mm[3]),
                                     pk2(mm[4], mm[5]), pk2(mm[6], mm[7]));
      *(uint4*)&k2[off] = make_uint4(pk2(ll[0], ll[1]), pk2(ll[2], ll[3]),
                                     pk2(ll[4], ll[5]), pk2(ll[6], ll[7]));
    }
  } else {
    short vb[4][8];
    #pragma unroll
    for (int i = 0; i < 4; ++i)
      #pragma unroll
      for (int jj = 0; jj < 8; ++jj)
        vb[i][jj] = f2bf(acc[i][jj] + bias[jj]);
    const int jbase = n * 64 + ty * 4;
    #pragma unroll
    for (int jj = 0; jj < 8; ++jj) {
      size_t off = (win * 32 + dh0 + jj) * 256 + jbase;
      *(uint2*)&vt[off] = make_uint2(pk2(vb[0][jj], vb[1][jj]),
                                     pk2(vb[2][jj], vb[3][jj]));
    }
  }
}

// ---------------- Kernel 2: windowed attention (all-LDS K, float bisect) -------
// One block per window, 256 thr = 4 waves; wave wv owns w-tile wt=wv, loops 4 n.
// R15/R17 spill data: spill magnitude tracks the # of GLOBAL-load streams in
// the unrolled QK loop (2->136MB, 1->73MB, 0 (R5)->none). Fix: stage ALL
// THREE K splits in LDS -> QK loop is pure ds_read+MFMA, no long-latency
// in-flight global results for the allocator to budget. LDS = 81920 B exactly
// (3x [256][36] K + vts[32][264] + pt stride 68 + merged sal/keep buffer)
// -> still 2 blocks/CU. Live ~= acc(64)+aq(12)+misc(~25) < 128 arch.
__global__ __launch_bounds__(256, 2) void k_attn(
    const float* __restrict__ qh, const short* __restrict__ k0,
    const short* __restrict__ k1, const short* __restrict__ k2,
    const short* __restrict__ vt, float* __restrict__ abar)
{
  __shared__ __align__(16) short ks0s[256][36];   // 18432 B
  __shared__ __align__(16) short ks1s[256][36];   // 18432 B
  __shared__ __align__(16) short ks2s[256][36];   // 18432 B
  __shared__ __align__(16) short vts[32][264];    // 16896 B
  __shared__ __align__(16) short pt[4][16][68];   // 8704 B (stride 68: 16-bank clean)
  __shared__ float salk[256];                      // 1024 B (saliency, then keepf)
                                                   // total 81920 B == 80 KB
  const int win = blockIdx.x;
  const int bh = win >> 6, l = win & 63;
  const int b = bh >> 2, h = bh & 3;
  const int tid = threadIdx.x;
  const int lane = tid & 63, wv = tid >> 6;
  const int g = lane >> 4, p = lane & 15;
  const int wt = wv;                          // 4 waves, 4 w-tiles

  const float* qw = qh + (size_t)win * 8192;

  // ---- stage K hi/mid/lo + V^T into LDS (once per window) ----
  {
    const uint4* s0 = (const uint4*)(k0 + (size_t)win * 8192);
    const uint4* s1 = (const uint4*)(k1 + (size_t)win * 8192);
    const uint4* s2 = (const uint4*)(k2 + (size_t)win * 8192);
    const uint4* sv = (const uint4*)(vt + (size_t)win * 8192);
    #pragma unroll
    for (int i = 0; i < 4; ++i) {
      int ci = tid + i * 256;                  // 1024 uint4 per tensor
      *(uint4*)&ks0s[ci >> 2][(ci & 3) * 8] = s0[ci];
      *(uint4*)&ks1s[ci >> 2][(ci & 3) * 8] = s1[ci];
      *(uint4*)&ks2s[ci >> 2][(ci & 3) * 8] = s2[ci];
      *(uint4*)&vts[ci >> 5][(ci & 31) * 8] = sv[ci];
    }
  }
  // ---- query saliency (FROZEN summation order) ----
  {
    const float4* qg2 = (const float4*)(qw + (size_t)tid * 32);
    float ss = 0.f;
    #pragma unroll
    for (int i = 0; i < 8; ++i) {
      float4 vv = qg2[i];
      ss += vv.x * vv.x + vv.y * vv.y + vv.z * vv.z + vv.w * vv.w;
    }
    salk[tid] = ss;
  }
  __syncthreads();
  if (wv == 0) {                              // exact top-192 saliency (FROZEN)
    // lane reads indices {lane+64s} then overwrites the same indices -> no alias
    float v[4]; bool selq[4];
    #pragma unroll
    for (int s = 0; s < 4; ++s) v[s] = salk[lane + 64 * s];
    topk_sel(v, KEEPQ, lane, selq);
    #pragma unroll
    for (int s = 0; s < 4; ++s) salk[lane + 64 * s] = selq[s] ? SCALE : 0.0f;
  }
  __syncthreads();

  float4v pacc0 = {0.f, 0.f, 0.f, 0.f};
  float4v pacc1 = {0.f, 0.f, 0.f, 0.f};
  short* ptw = &pt[wv][0][0];                 // [16][68]

  for (int n = 0; n < 4; ++n) {
    const int qbase = n * 64 + wt * 16;
    const float kfp = salk[qbase + p];        // per-query (col p) keep factor
    const bool kept = (kfp != 0.0f);

    // ---- Q B-fragment: scale+mask then bf16x3 split (FROZEN values) ----
    short8v aq0, aq1, aq2;
    {
      const float* qrow = qw + (size_t)(qbase + p) * 32 + g * 8;
      float4 qa = *(const float4*)qrow;
      float4 qb = *(const float4*)(qrow + 4);
      float qv[8] = {qa.x, qa.y, qa.z, qa.w, qb.x, qb.y, qb.z, qb.w};
      #pragma unroll
      for (int e = 0; e < 8; ++e) {
        short hh, mm, ll;
        split3(qv[e] * kfp, hh, mm, ll);
        aq0[e] = hh; aq1[e] = mm; aq2[e] = ll;
      }
    }

    // ---- QK^T swapped: acc[c][r] = S[key 16c+4g+r][query qbase+p]; FROZEN ----
    // Pure LDS reads: no global in-flight registers for the allocator to budget.
    float4v acc[16];
    #pragma unroll
    for (int c = 0; c < 16; ++c) {
      const short8v b0 = *(const short8v*)&ks0s[c * 16 + p][g * 8];
      const short8v b1 = *(const short8v*)&ks1s[c * 16 + p][g * 8];
      const short8v b2 = *(const short8v*)&ks2s[c * 16 + p][g * 8];
      float4v a = {0.f, 0.f, 0.f, 0.f};
      a = __builtin_amdgcn_mfma_f32_16x16x32_bf16(b0, aq0, a, 0, 0, 0);
      a = __builtin_amdgcn_mfma_f32_16x16x32_bf16(b0, aq1, a, 0, 0, 0);
      a = __builtin_amdgcn_mfma_f32_16x16x32_bf16(b0, aq2, a, 0, 0, 0);
      a = __builtin_amdgcn_mfma_f32_16x16x32_bf16(b1, aq0, a, 0, 0, 0);
      a = __builtin_amdgcn_mfma_f32_16x16x32_bf16(b1, aq1, a, 0, 0, 0);
      a = __builtin_amdgcn_mfma_f32_16x16x32_bf16(b2, aq0, a, 0, 0, 0);
      acc[c] = a;
    }

    // ---- float max/min reduce over the query's 256 keys ----
    float fmx = acc[0][0], fmn = acc[0][0];
    #pragma unroll
    for (int c = 0; c < 16; ++c) {
      #pragma unroll
      for (int r = 0; r < 4; ++r) {
        fmx = fmaxf(fmx, acc[c][r]);
        fmn = fminf(fmn, acc[c][r]);
      }
    }
    fmx = fmaxf(fmx, __shfl_xor(fmx, 16));
    fmn = fminf(fmn, __shfl_xor(fmn, 16));
    fmx = fmaxf(fmx, __shfl_xor(fmx, 32));
    fmn = fminf(fmn, __shfl_xor(fmn, 32));
    const uint32_t umaxu = fmap(fmx), uminu = fmap(fmn);
    const float fm = unmap(umaxu);            // canonical (+0) exact max

    // ---- exact top-64 threshold: bisection with FLOAT compares ----
    uint32_t piv = 0u; int cnt = 256; int sb = -1; bool bdone = true;
    if (kept) {
      uint32_t du = umaxu ^ uminu;
      if (du != 0u) {
        sb = 31 - __clz(du);
        piv = (sb >= 31) ? 0u : (umaxu & (0xFFFFFFFFu << (sb + 1)));
        bdone = false;
      } else { piv = umaxu; }                 // all equal -> tie path
    }
    for (int bit = 31; bit >= 0; --bit) {
      if (__all(bdone)) break;
      const uint32_t cand = piv | (1u << bit);
      const float tf = unmap(cand);
      int cc = 0;
      #pragma unroll
      for (int c = 0; c < 16; ++c) {
        #pragma unroll
        for (int r = 0; r < 4; ++r) cc += (acc[c][r] >= tf) ? 1 : 0;
      }
      cc += __shfl_xor(cc, 16);
      cc += __shfl_xor(cc, 32);
      if (!bdone && bit <= sb && cc >= 64) {
        piv = cand; cnt = cc;
        if (cc == 64) bdone = true;
      }
    }
    const float Tf = unmap(piv);

    // ---- selection mask (bit 4c+r), exact tie-break by key index ----
    uint64_t selm = 0ull;
    if (kept) {
      if (cnt == 64) {
        #pragma unroll
        for (int c = 0; c < 16; ++c)
          #pragma unroll
          for (int r = 0; r < 4; ++r)
            selm |= (acc[c][r] >= Tf) ? (1ull << (4 * c + r)) : 0ull;
      } else {
        // rare: ties at Tf. Register-light per-c incremental scan (R17).
        int gtc = 0;
        #pragma unroll
        for (int c = 0; c < 16; ++c)
          #pragma unroll
          for (int r = 0; r < 4; ++r) gtc += (acc[c][r] > Tf) ? 1 : 0;
        gtc += __shfl_xor(gtc, 16);
        gtc += __shfl_xor(gtc, 32);
        const int need = 64 - gtc;
        int pref = 0;                          // eq count in key blocks c' < c
        #pragma unroll
        for (int c = 0; c < 16; ++c) {
          int on = 0;                          // eq nibble for this lane's 4 keys
          #pragma unroll
          for (int r = 0; r < 4; ++r) on |= (acc[c][r] == Tf) ? (1 << r) : 0;
          const int cn = __popc(on);
          const int cnA = __shfl_xor(cn, 16);  // group g^1
          const int cnB = __shfl_xor(cn, 32);  // group g^2
          const int cnC = __shfl_xor(cnA, 32); // group g^3
          const int gs = (((g ^ 1) < g) ? cnA : 0)
                       + (((g ^ 2) < g) ? cnB : 0)
                       + (((g ^ 3) < g) ? cnC : 0);
          #pragma unroll
          for (int r = 0; r < 4; ++r) {
            bool s2;
            if (acc[c][r] > Tf) s2 = true;
            else if (acc[c][r] == Tf) {
              int before = pref + gs + __popc(on & ((1 << r) - 1));
              s2 = (before < need);
            } else s2 = false;
            selm |= s2 ? (1ull << (4 * c + r)) : 0ull;
          }
          pref += cn + cnA + cnB + cnC;
        }
      }
    }

    // ---- e = exp(S - fm) on selected; OVERWRITE acc in place; esum (FROZEN) ----
    float esum = 0.f;
    #pragma unroll
    for (int c = 0; c < 16; ++c) {
      #pragma unroll
      for (int r = 0; r < 4; ++r) {
        float e;
        if (kept)
          e = ((selm >> (4 * c + r)) & 1ull) ? __expf(acc[c][r] - fm) : 0.0f;
        else
          e = (c < 4) ? 0.015625f : 0.0f;    // pruned: uniform 1/64 over first 64 keys
        acc[c][r] = e;
        esum += e;
      }
    }
    esum += __shfl_xor(esum, 16);
    esum += __shfl_xor(esum, 32);
    const float inv = kept ? (1.0f / esum) : 1.0f;

    // ---- PV: stage P^T per 2-kk block, then MFMA (FROZEN chain order) ----
    #pragma unroll
    for (int t = 0; t < 4; ++t) {
      #pragma unroll
      for (int kq = 0; kq < 2; ++kq) {
        const int kk = 2 * t + kq;
        const int ce = 2 * kk, co = ce + 1;
        uint2 w0 = make_uint2(pk2(f2bf(acc[ce][0] * inv), f2bf(acc[ce][1] * inv)),
                              pk2(f2bf(acc[ce][2] * inv), f2bf(acc[ce][3] * inv)));
        uint2 w1 = make_uint2(pk2(f2bf(acc[co][0] * inv), f2bf(acc[co][1] * inv)),
                              pk2(f2bf(acc[co][2] * inv), f2bf(acc[co][3] * inv)));
        *(uint2*)&ptw[p * 68 + kq * 32 + 4 * g] = w0;
        *(uint2*)&ptw[p * 68 + kq * 32 + 16 + 4 * g] = w1;
      }
      // cross-lane visibility of this wave's writes (no HIP-level dependency)
      asm volatile("s_waitcnt lgkmcnt(0)" ::: "memory");
      __builtin_amdgcn_sched_barrier(0);
      #pragma unroll
      for (int kq = 0; kq < 2; ++kq) {
        const int kk = 2 * t + kq;
        short8v pa = *(const short8v*)&ptw[p * 68 + kq * 32 + 8 * g];
        short8v v0 = *(const short8v*)&vts[p][kk * 32 + 8 * g];
        short8v v1 = *(const short8v*)&vts[16 + p][kk * 32 + 8 * g];
        pacc0 = __builtin_amdgcn_mfma_f32_16x16x32_bf16(pa, v0, pacc0, 0, 0, 0);
        pacc1 = __builtin_amdgcn_mfma_f32_16x16x32_bf16(pa, v1, pacc1, 0, 0, 0);
      }
    }
  }

  // ---- write abar = mean over n (each wave owns its w-tile; no reduction) ----
  #pragma unroll
  for (int rr = 0; rr < 4; ++rr) {
    const int w = wt * 16 + g * 4 + rr;
    size_t o = ((size_t)(b * 64 + l) * 64 + w) * 128 + h * 32;
    abar[o + p] = pacc0[rr] * 0.25f;
    abar[o + 16 + p] = pacc1[rr] * 0.25f;
  }
}

// ---------------- Kernel 3: final projection (FROZEN) ----------------
__global__ __launch_bounds__(256) void k_proj(
    const float* __restrict__ abar, const float* __restrict__ W,
    const float* __restrict__ bi, float* __restrict__ out)
{
  __shared__ float xs[64 * 132];
  const int tile = blockIdx.x;
  const int tid = threadIdx.x;
  const float4* xg = (const float4*)(abar + (size_t)tile * 64 * 128);
  #pragma unroll
  for (int i = 0; i < 8; ++i) {
    int idx = tid + i * 256;
    int r = idx >> 5, c = (idx & 31) * 4;
    *(float4*)&xs[r * 132 + c] = xg[idx];
  }
  __syncthreads();

  const int ty = tid >> 4, tx = tid & 15;
  float acc[4][8];
  #pragma unroll
  for (int i = 0; i < 4; ++i)
    #pragma unroll
    for (int j = 0; j < 8; ++j) acc[i][j] = 0.f;

  #pragma unroll 2
  for (int kk = 0; kk < 128; kk += 4) {
    float aa[4][4];
    #pragma unroll
    for (int i = 0; i < 4; ++i)
      *(float4*)&aa[i][0] = *(const float4*)&xs[(ty * 4 + i) * 132 + kk];
    #pragma unroll
    for (int t2 = 0; t2 < 4; ++t2) {
      const float4 w0 = *(const float4*)&W[(kk + t2) * 128 + tx * 8];
      const float4 w1 = *(const float4*)&W[(kk + t2) * 128 + tx * 8 + 4];
      #pragma unroll
      for (int i = 0; i < 4; ++i) {
        acc[i][0] = fmaf(aa[i][t2], w0.x, acc[i][0]);
        acc[i][1] = fmaf(aa[i][t2], w0.y, acc[i][1]);
        acc[i][2] = fmaf(aa[i][t2], w0.z, acc[i][2]);
        acc[i][3] = fmaf(aa[i][t2], w0.w, acc[i][3]);
        acc[i][4] = fmaf(aa[i][t2], w1.x, acc[i][4]);
        acc[i][5] = fmaf(aa[i][t2], w1.y, acc[i][5]);
        acc[i][6] = fmaf(aa[i][t2], w1.z, acc[i][6]);
        acc[i][7] = fmaf(aa[i][t2], w1.w, acc[i][7]);
      }
    }
  }
  #pragma unroll
  for (int i = 0; i < 4; ++i) {
    size_t row = (size_t)tile * 64 + ty * 4 + i;
    float4 o0 = make_float4(acc[i][0] + bi[tx * 8 + 0], acc[i][1] + bi[tx * 8 + 1],
                            acc[i][2] + bi[tx * 8 + 2], acc[i][3] + bi[tx * 8 + 3]);
    float4 o1 = make_float4(acc[i][4] + bi[tx * 8 + 4], acc[i][5] + bi[tx * 8 + 5],
                            acc[i][6] + bi[tx * 8 + 6], acc[i][7] + bi[tx * 8 + 7]);
    *(float4*)&out[row * 128 + tx * 8] = o0;
    *(float4*)&out[row * 128 + tx * 8 + 4] = o1;
  }
}

extern "C" void kernel_launch(void* const* d_in, const int* in_sizes, int n_in,
                              void* d_out, int out_size, void* d_ws, size_t ws_size,
                              hipStream_t stream) {
  (void)in_sizes; (void)n_in; (void)out_size; (void)ws_size;
  const float* xq   = (const float*)d_in[0];
  const float* xk   = (const float*)d_in[1];
  const float* xv   = (const float*)d_in[2];
  const float* gq   = (const float*)d_in[3];
  const float* beq  = (const float*)d_in[4];
  const float* gk   = (const float*)d_in[5];
  const float* bek  = (const float*)d_in[6];
  const float* gv   = (const float*)d_in[7];
  const float* bev  = (const float*)d_in[8];
  const float* wq   = (const float*)d_in[9];
  const float* biq  = (const float*)d_in[10];
  const float* wk   = (const float*)d_in[11];
  const float* bik  = (const float*)d_in[12];
  const float* wv   = (const float*)d_in[13];
  const float* biv  = (const float*)d_in[14];
  const float* wpr  = (const float*)d_in[15];
  const float* bpr  = (const float*)d_in[16];

  // ws layout (109,051,904 B total == proven footprint):
  char* ws = (char*)d_ws;
  float* qh  = (float*)(ws);                       // 33,554,432 B
  short* k0  = (short*)(ws + 33554432);            // 16,777,216 B
  short* k1  = (short*)(ws + 50331648);            // 16,777,216 B
  short* k2  = (short*)(ws + 67108864);            // 16,777,216 B
  short* vt  = (short*)(ws + 83886080);            // 16,777,216 B
  float* abar = (float*)(ws + 100663296);          //  8,388,608 B

  k_lnproj<<<dim3(1024, 3), 256, 0, stream>>>(xq, xk, xv, gq, beq, gk, bek, gv, bev,
                                              wq, biq, wk, bik, wv, biv,
                                              qh, k0, k1, k2, vt);
  k_attn<<<1024, 256, 0, stream>>>(qh, k0, k1, k2, vt, abar);
  k_proj<<<256, 256, 0, stream>>>(abar, wpr, bpr, (float*)d_out);
}